// Round 1
// baseline (483.004 us; speedup 1.0000x reference)
//
#include <hip/hip_runtime.h>
#include <hip/hip_bf16.h>
#include <math.h>

// Problem constants (B=64, N=512, D=512, H=4D=2048, R=32 routes)
#define B_ 64
#define N_ 512
#define D_ 512
#define H_ 2048
#define R_ 32
#define M_ (B_ * N_)  // 32768 token rows

typedef __bf16 bf16x8 __attribute__((ext_vector_type(8)));
typedef float f32x4 __attribute__((ext_vector_type(4)));

// ---------------------------------------------------------------------------
// async global->LDS copy, 16B per lane. LDS dest is wave-uniform base + lane*16.
// ---------------------------------------------------------------------------
__device__ __forceinline__ void async_ld16(const void* g, void* l) {
  __builtin_amdgcn_global_load_lds((__attribute__((address_space(1))) void*)g,
                                   (__attribute__((address_space(3))) void*)l,
                                   16, 0, 0);
}

// ---------------------------------------------------------------------------
// token_mask dtype detection: harness may pass bool as int32 or as raw bytes.
// If int32 with values 0/1, bytes at index % 4 != 0 are all zero. If raw bytes
// (~70% ones), nonzero bytes appear at those positions with certainty.
// ---------------------------------------------------------------------------
__global__ void mask_detect_kernel(const unsigned char* __restrict__ raw,
                                   int* __restrict__ flag) {
  __shared__ int f;
  if (threadIdx.x == 0) f = 0;
  __syncthreads();
  int loc = 0;
  for (int i = threadIdx.x; i < M_; i += 256)
    if ((i & 3) != 0 && raw[i] != 0) loc = 1;
  if (loc) f = 1;  // benign race
  __syncthreads();
  if (threadIdx.x == 0) flag[0] = f;
}

__global__ void mask_norm_kernel(const void* __restrict__ raw,
                                 const int* __restrict__ flag,
                                 int* __restrict__ mask) {
  int i = blockIdx.x * 256 + threadIdx.x;
  int v = flag[0] ? (int)((const unsigned char*)raw)[i] : ((const int*)raw)[i];
  mask[i] = (v != 0) ? 1 : 0;
}

// ---------------------------------------------------------------------------
// Transpose + cast f32 [R,C] -> bf16 [C,R] (for MFMA B-operand K-contiguity)
// ---------------------------------------------------------------------------
__global__ __launch_bounds__(256) void transpose_cast_kernel(
    const float* __restrict__ src, __hip_bfloat16* __restrict__ dst, int R, int C) {
  __shared__ float tile[64][65];
  const int c0 = blockIdx.x * 64, r0 = blockIdx.y * 64;
  const int tx = threadIdx.x & 63, ty = threadIdx.x >> 6;
  for (int r = ty; r < 64; r += 4)
    tile[r][tx] = src[(size_t)(r0 + r) * C + c0 + tx];
  __syncthreads();
  for (int r = ty; r < 64; r += 4)
    dst[(size_t)(c0 + r) * R + r0 + tx] = __float2bfloat16(tile[tx][r]);
}

// ---------------------------------------------------------------------------
// LayerNorm rows -> bf16 (one wave per 512-elem row, 8 rows per block)
// ---------------------------------------------------------------------------
__global__ __launch_bounds__(512) void ln_rows_kernel(
    const float* __restrict__ src, const float* __restrict__ gw,
    const float* __restrict__ gb, __hip_bfloat16* __restrict__ dst) {
  const int wv = threadIdx.x >> 6, lane = threadIdx.x & 63;
  const int row = blockIdx.x * 8 + wv;
  const float* p = src + (size_t)row * D_ + lane * 8;
  const float4 v0 = *(const float4*)p;
  const float4 v1 = *(const float4*)(p + 4);
  float s = v0.x + v0.y + v0.z + v0.w + v1.x + v1.y + v1.z + v1.w;
  float ss = v0.x * v0.x + v0.y * v0.y + v0.z * v0.z + v0.w * v0.w +
             v1.x * v1.x + v1.y * v1.y + v1.z * v1.z + v1.w * v1.w;
#pragma unroll
  for (int m = 32; m > 0; m >>= 1) {
    s += __shfl_xor(s, m);
    ss += __shfl_xor(ss, m);
  }
  const float mu = s * (1.0f / D_);
  const float rstd = rsqrtf(ss * (1.0f / D_) - mu * mu + 1e-5f);
  const float4 g0 = *(const float4*)(gw + lane * 8);
  const float4 g1 = *(const float4*)(gw + lane * 8 + 4);
  const float4 b0 = *(const float4*)(gb + lane * 8);
  const float4 b1 = *(const float4*)(gb + lane * 8 + 4);
  const float vv[8] = {v0.x, v0.y, v0.z, v0.w, v1.x, v1.y, v1.z, v1.w};
  const float gg[8] = {g0.x, g0.y, g0.z, g0.w, g1.x, g1.y, g1.z, g1.w};
  const float bb[8] = {b0.x, b0.y, b0.z, b0.w, b1.x, b1.y, b1.z, b1.w};
  union { __hip_bfloat16 h[8]; uint4 u; } pk;
#pragma unroll
  for (int t = 0; t < 8; ++t)
    pk.h[t] = __float2bfloat16((vv[t] - mu) * rstd * gg[t] + bb[t]);
  *(uint4*)(dst + (size_t)row * D_ + lane * 8) = pk.u;
}

// ---------------------------------------------------------------------------
// GEMM1: C = gelu(A @ Bt^T + bias), bf16 in/out, fp32 MFMA accumulate.
// A [M,K] lda=K, Bt [N,K] ldb=K (pre-transposed weight), C [M,ldc] bf16.
// 128x128 tile, BK=32, 4 waves, each wave 4x4 of 16x16x32 MFMA (m97 structure).
// ---------------------------------------------------------------------------
__global__ __launch_bounds__(256, 2) void gemm_bias_gelu_kernel(
    const __hip_bfloat16* __restrict__ A, const __hip_bfloat16* __restrict__ Bt,
    const float* __restrict__ bias, __hip_bfloat16* __restrict__ C,
    int M, int N, int K, int ldc) {
  __shared__ alignas(16) unsigned short As[128 * 32];
  __shared__ alignas(16) unsigned short Bs[128 * 32];
  const int tid = threadIdx.x;
  const int w = tid >> 6;
  const int lane = tid & 63;
  const int rowBase = blockIdx.y * 128;
  const int colBase = blockIdx.x * 128;
  const int warpRow = w >> 1;
  const int warpCol = w & 1;
  const int q = lane >> 4;       // 0..3 (quad)
  const int mr = lane & 15;      // free-dim index within 16
  const int srow = lane >> 2;    // staging: row within 16-row chunk
  const int skc = (lane & 3) * 8;  // staging: k offset (8 bf16 = 16B)

  f32x4 acc[4][4] = {};

  for (int k0 = 0; k0 < K; k0 += 32) {
    __syncthreads();  // prior iter's LDS reads done
#pragma unroll
    for (int i = 0; i < 2; ++i) {
      const int c = i * 4 + w;           // chunk 0..7 (16 rows each)
      const int row = c * 16 + srow;
      async_ld16(&A[(size_t)(rowBase + row) * K + (k0 + skc)], (void*)&As[c * 512]);
      async_ld16(&Bt[(size_t)(colBase + row) * K + (k0 + skc)], (void*)&Bs[c * 512]);
    }
    __syncthreads();  // staging visible (vmcnt drained by barrier)
    bf16x8 af[4], bf[4];
#pragma unroll
    for (int i = 0; i < 4; ++i)
      af[i] = *reinterpret_cast<const bf16x8*>(&As[(warpRow * 64 + i * 16 + mr) * 32 + q * 8]);
#pragma unroll
    for (int j = 0; j < 4; ++j)
      bf[j] = *reinterpret_cast<const bf16x8*>(&Bs[(warpCol * 64 + j * 16 + mr) * 32 + q * 8]);
#pragma unroll
    for (int i = 0; i < 4; ++i)
#pragma unroll
      for (int j = 0; j < 4; ++j)
        acc[i][j] = __builtin_amdgcn_mfma_f32_16x16x32_bf16(af[i], bf[j], acc[i][j], 0, 0, 0);
  }

  // epilogue: + bias, exact GELU, bf16 store. C/D layout: n=lane&15, m=q*4+reg.
#pragma unroll
  for (int j = 0; j < 4; ++j) {
    const int n = colBase + warpCol * 64 + j * 16 + mr;
    const float bv = bias[n];
#pragma unroll
    for (int i = 0; i < 4; ++i) {
#pragma unroll
      for (int r = 0; r < 4; ++r) {
        const int m = rowBase + warpRow * 64 + i * 16 + q * 4 + r;
        float v = acc[i][j][r] + bv;
        v = 0.5f * v * (1.0f + erff(v * 0.70710678118f));
        C[(size_t)m * ldc + n] = __float2bfloat16(v);
      }
    }
  }
}

// ---------------------------------------------------------------------------
// GEMM2: X = (first ? resid + bias : X) + A @ Bt^T   (fp32 output, residual)
// A [M,K] lda=K (h buffer), Bt rows at ldb stride (w2t, k-offset via pointer).
// ---------------------------------------------------------------------------
__global__ __launch_bounds__(256, 2) void gemm_acc_kernel(
    const __hip_bfloat16* __restrict__ A, const __hip_bfloat16* __restrict__ Bt,
    const float* __restrict__ bias, const float* __restrict__ resid,
    float* __restrict__ X, int M, int N, int K, int ldb, int first) {
  __shared__ alignas(16) unsigned short As[128 * 32];
  __shared__ alignas(16) unsigned short Bs[128 * 32];
  const int tid = threadIdx.x;
  const int w = tid >> 6;
  const int lane = tid & 63;
  const int rowBase = blockIdx.y * 128;
  const int colBase = blockIdx.x * 128;
  const int warpRow = w >> 1;
  const int warpCol = w & 1;
  const int q = lane >> 4;
  const int mr = lane & 15;
  const int srow = lane >> 2;
  const int skc = (lane & 3) * 8;

  f32x4 acc[4][4] = {};

  for (int k0 = 0; k0 < K; k0 += 32) {
    __syncthreads();
#pragma unroll
    for (int i = 0; i < 2; ++i) {
      const int c = i * 4 + w;
      const int row = c * 16 + srow;
      async_ld16(&A[(size_t)(rowBase + row) * K + (k0 + skc)], (void*)&As[c * 512]);
      async_ld16(&Bt[(size_t)(colBase + row) * ldb + (k0 + skc)], (void*)&Bs[c * 512]);
    }
    __syncthreads();
    bf16x8 af[4], bf[4];
#pragma unroll
    for (int i = 0; i < 4; ++i)
      af[i] = *reinterpret_cast<const bf16x8*>(&As[(warpRow * 64 + i * 16 + mr) * 32 + q * 8]);
#pragma unroll
    for (int j = 0; j < 4; ++j)
      bf[j] = *reinterpret_cast<const bf16x8*>(&Bs[(warpCol * 64 + j * 16 + mr) * 32 + q * 8]);
#pragma unroll
    for (int i = 0; i < 4; ++i)
#pragma unroll
      for (int j = 0; j < 4; ++j)
        acc[i][j] = __builtin_amdgcn_mfma_f32_16x16x32_bf16(af[i], bf[j], acc[i][j], 0, 0, 0);
  }

#pragma unroll
  for (int j = 0; j < 4; ++j) {
    const int n = colBase + warpCol * 64 + j * 16 + mr;
    const float bv = bias[n];
#pragma unroll
    for (int i = 0; i < 4; ++i) {
#pragma unroll
      for (int r = 0; r < 4; ++r) {
        const int m = rowBase + warpRow * 64 + i * 16 + q * 4 + r;
        const size_t idx = (size_t)m * N + n;
        const float base = first ? (resid[idx] + bv) : X[idx];
        X[idx] = base + acc[i][j][r];
      }
    }
  }
}

// ---------------------------------------------------------------------------
// tok_logits[row] = LN(x_row; wp_g, wp_b) . wp_w + wp_bias  (one wave per row)
// ---------------------------------------------------------------------------
__global__ __launch_bounds__(512) void token_logits_kernel(
    const float* __restrict__ X, const float* __restrict__ gw,
    const float* __restrict__ gb, const float* __restrict__ ww,
    const float* __restrict__ wbias, float* __restrict__ logits) {
  const int wv = threadIdx.x >> 6, lane = threadIdx.x & 63;
  const int row = blockIdx.x * 8 + wv;
  const float* p = X + (size_t)row * D_ + lane * 8;
  const float4 v0 = *(const float4*)p;
  const float4 v1 = *(const float4*)(p + 4);
  float s = v0.x + v0.y + v0.z + v0.w + v1.x + v1.y + v1.z + v1.w;
  float ss = v0.x * v0.x + v0.y * v0.y + v0.z * v0.z + v0.w * v0.w +
             v1.x * v1.x + v1.y * v1.y + v1.z * v1.z + v1.w * v1.w;
#pragma unroll
  for (int m = 32; m > 0; m >>= 1) {
    s += __shfl_xor(s, m);
    ss += __shfl_xor(ss, m);
  }
  const float mu = s * (1.0f / D_);
  const float rstd = rsqrtf(ss * (1.0f / D_) - mu * mu + 1e-5f);
  const float4 g0 = *(const float4*)(gw + lane * 8);
  const float4 g1 = *(const float4*)(gw + lane * 8 + 4);
  const float4 b0 = *(const float4*)(gb + lane * 8);
  const float4 b1 = *(const float4*)(gb + lane * 8 + 4);
  const float4 w0 = *(const float4*)(ww + lane * 8);
  const float4 w1 = *(const float4*)(ww + lane * 8 + 4);
  const float vv[8] = {v0.x, v0.y, v0.z, v0.w, v1.x, v1.y, v1.z, v1.w};
  const float gg[8] = {g0.x, g0.y, g0.z, g0.w, g1.x, g1.y, g1.z, g1.w};
  const float bb[8] = {b0.x, b0.y, b0.z, b0.w, b1.x, b1.y, b1.z, b1.w};
  const float wwv[8] = {w0.x, w0.y, w0.z, w0.w, w1.x, w1.y, w1.z, w1.w};
  float a = 0.f;
#pragma unroll
  for (int t = 0; t < 8; ++t) a += ((vv[t] - mu) * rstd * gg[t] + bb[t]) * wwv[t];
#pragma unroll
  for (int m = 32; m > 0; m >>= 1) a += __shfl_xor(a, m);
  if (lane == 0) logits[row] = a + wbias[0];
}

// ---------------------------------------------------------------------------
// Per-(b,route) masked softmax pool over tokens -> routes [B,R,D], present [B,R]
// ---------------------------------------------------------------------------
__global__ __launch_bounds__(256) void route_pool_kernel(
    const float* __restrict__ X, const float* __restrict__ logits,
    const int* __restrict__ route_ids, const int* __restrict__ maskN,
    float* __restrict__ routes, int* __restrict__ present) {
  const int b = blockIdx.x >> 5;
  const int r = blockIdx.x & 31;
  __shared__ int cnt;
  __shared__ int ls[N_];
  __shared__ float lw[N_];
  if (threadIdx.x == 0) cnt = 0;
  __syncthreads();
  for (int n = threadIdx.x; n < N_; n += 256) {
    if (route_ids[n] == r && maskN[b * N_ + n]) {
      int p = atomicAdd(&cnt, 1);
      ls[p] = n;
      lw[p] = logits[b * N_ + n];
    }
  }
  __syncthreads();
  const int c = cnt;
  if (threadIdx.x == 0 && c > 0) {
    float mx = -1e30f;
    for (int i = 0; i < c; ++i) mx = fmaxf(mx, lw[i]);
    float sm = 0.f;
    for (int i = 0; i < c; ++i) {
      const float e = expf(lw[i] - mx);
      lw[i] = e;
      sm += e;
    }
    const float inv = 1.0f / sm;
    for (int i = 0; i < c; ++i) lw[i] *= inv;
  }
  __syncthreads();
  float a0 = 0.f, a1 = 0.f;
  for (int i = 0; i < c; ++i) {
    const float* xr = X + ((size_t)b * N_ + ls[i]) * D_;
    const float wgt = lw[i];
    a0 += wgt * xr[threadIdx.x];
    a1 += wgt * xr[threadIdx.x + 256];
  }
  float* outp = routes + ((size_t)b * R_ + r) * D_;
  outp[threadIdx.x] = a0;
  outp[threadIdx.x + 256] = a1;
  if (threadIdx.x == 0) present[b * R_ + r] = (c > 0) ? 1 : 0;
}

// ---------------------------------------------------------------------------
// Final pool: per batch: rl = LN(routes).rp_w + rp_bias; softmax over present
// routes; out = sum_r w_r * routes[b,r,:]   (one block of 512 per batch)
// ---------------------------------------------------------------------------
__global__ __launch_bounds__(512) void final_pool_kernel(
    const float* __restrict__ routes, const int* __restrict__ present,
    const float* __restrict__ gw, const float* __restrict__ gb,
    const float* __restrict__ ww, const float* __restrict__ wbias,
    float* __restrict__ out) {
  const int b = blockIdx.x;
  const int wv = threadIdx.x >> 6, lane = threadIdx.x & 63;
  __shared__ float srw[R_];
  __shared__ float srl[R_];
  for (int r = wv; r < R_; r += 8) {
    const float* p = routes + ((size_t)b * R_ + r) * D_ + lane * 8;
    const float4 v0 = *(const float4*)p;
    const float4 v1 = *(const float4*)(p + 4);
    float s = v0.x + v0.y + v0.z + v0.w + v1.x + v1.y + v1.z + v1.w;
    float ss = v0.x * v0.x + v0.y * v0.y + v0.z * v0.z + v0.w * v0.w +
               v1.x * v1.x + v1.y * v1.y + v1.z * v1.z + v1.w * v1.w;
#pragma unroll
    for (int m = 32; m > 0; m >>= 1) {
      s += __shfl_xor(s, m);
      ss += __shfl_xor(ss, m);
    }
    const float mu = s * (1.0f / D_);
    const float rstd = rsqrtf(ss * (1.0f / D_) - mu * mu + 1e-5f);
    const float4 g0 = *(const float4*)(gw + lane * 8);
    const float4 g1 = *(const float4*)(gw + lane * 8 + 4);
    const float4 b0 = *(const float4*)(gb + lane * 8);
    const float4 b1 = *(const float4*)(gb + lane * 8 + 4);
    const float4 w0 = *(const float4*)(ww + lane * 8);
    const float4 w1 = *(const float4*)(ww + lane * 8 + 4);
    const float vv[8] = {v0.x, v0.y, v0.z, v0.w, v1.x, v1.y, v1.z, v1.w};
    const float gg[8] = {g0.x, g0.y, g0.z, g0.w, g1.x, g1.y, g1.z, g1.w};
    const float bb[8] = {b0.x, b0.y, b0.z, b0.w, b1.x, b1.y, b1.z, b1.w};
    const float wwv[8] = {w0.x, w0.y, w0.z, w0.w, w1.x, w1.y, w1.z, w1.w};
    float a = 0.f;
#pragma unroll
    for (int t = 0; t < 8; ++t) a += ((vv[t] - mu) * rstd * gg[t] + bb[t]) * wwv[t];
#pragma unroll
    for (int m = 32; m > 0; m >>= 1) a += __shfl_xor(a, m);
    if (lane == 0) srl[r] = a + wbias[0];
  }
  __syncthreads();
  if (threadIdx.x == 0) {
    float mx = -1e30f;
    for (int r = 0; r < R_; ++r)
      if (present[b * R_ + r]) mx = fmaxf(mx, srl[r]);
    float sm = 0.f;
    for (int r = 0; r < R_; ++r) {
      const float e = present[b * R_ + r] ? expf(srl[r] - mx) : 0.f;
      srw[r] = e;
      sm += e;
    }
    const float inv = (sm > 0.f) ? 1.0f / sm : 0.f;
    for (int r = 0; r < R_; ++r) srw[r] *= inv;
  }
  __syncthreads();
  const int d = threadIdx.x;
  float a = 0.f;
  for (int r = 0; r < R_; ++r) a += srw[r] * routes[((size_t)b * R_ + r) * D_ + d];
  out[(size_t)b * D_ + d] = a;
}

// ---------------------------------------------------------------------------
extern "C" void kernel_launch(void* const* d_in, const int* in_sizes, int n_in,
                              void* d_out, int out_size, void* d_ws, size_t ws_size,
                              hipStream_t stream) {
  const float* tokens = (const float*)d_in[0];
  const void* mask_raw = d_in[1];
  const int* route_ids = (const int*)d_in[2];
  const float* ln1_g = (const float*)d_in[3];
  const float* ln1_b = (const float*)d_in[4];
  const float* w1 = (const float*)d_in[5];
  const float* b1 = (const float*)d_in[6];
  const float* w2 = (const float*)d_in[7];
  const float* b2 = (const float*)d_in[8];
  const float* wp_g = (const float*)d_in[9];
  const float* wp_b = (const float*)d_in[10];
  const float* wp_w = (const float*)d_in[11];
  const float* wp_bias = (const float*)d_in[12];
  const float* rp_g = (const float*)d_in[13];
  const float* rp_b = (const float*)d_in[14];
  const float* rp_w = (const float*)d_in[15];
  const float* rp_bias = (const float*)d_in[16];
  float* out = (float*)d_out;

  char* ws = (char*)d_ws;
  size_t off = 0;
  auto carve = [&](size_t bytes) -> void* {
    void* p = ws + off;
    off = (off + bytes + 255) & ~(size_t)255;
    return p;
  };

  __hip_bfloat16* w1t = (__hip_bfloat16*)carve((size_t)H_ * D_ * 2);  // [H, D]
  __hip_bfloat16* w2t = (__hip_bfloat16*)carve((size_t)D_ * H_ * 2);  // [D, H]
  __hip_bfloat16* aBf = (__hip_bfloat16*)carve((size_t)M_ * D_ * 2);  // LN1 out
  float* X = (float*)carve((size_t)M_ * D_ * 4);                      // FFN out + resid
  float* tlog = (float*)carve((size_t)M_ * 4);
  int* maskN = (int*)carve((size_t)M_ * 4);
  int* flag = (int*)carve(256);
  int* present = (int*)carve((size_t)B_ * R_ * 4);
  float* routes = (float*)carve((size_t)B_ * R_ * D_ * 4);

  // h buffer: prefer full [M, H] bf16 (128 MB); fall back to K-grouped FFN.
  int G = 1;
  while (G < 16 && off + (size_t)M_ * (H_ / G) * 2 > ws_size) G <<= 1;
  const int Hg = H_ / G;
  __hip_bfloat16* hbuf = (__hip_bfloat16*)carve((size_t)M_ * Hg * 2);

  mask_detect_kernel<<<1, 256, 0, stream>>>((const unsigned char*)mask_raw, flag);
  mask_norm_kernel<<<M_ / 256, 256, 0, stream>>>(mask_raw, flag, maskN);
  transpose_cast_kernel<<<dim3(H_ / 64, D_ / 64), 256, 0, stream>>>(w1, w1t, D_, H_);
  transpose_cast_kernel<<<dim3(D_ / 64, H_ / 64), 256, 0, stream>>>(w2, w2t, H_, D_);
  ln_rows_kernel<<<M_ / 8, 512, 0, stream>>>(tokens, ln1_g, ln1_b, aBf);

  for (int g = 0; g < G; ++g) {
    gemm_bias_gelu_kernel<<<dim3(Hg / 128, M_ / 128), 256, 0, stream>>>(
        aBf, w1t + (size_t)g * Hg * D_, b1 + (size_t)g * Hg, hbuf, M_, Hg, D_, Hg);
    gemm_acc_kernel<<<dim3(D_ / 128, M_ / 128), 256, 0, stream>>>(
        hbuf, w2t + (size_t)g * Hg, b2, tokens, X, M_, D_, Hg, H_, (g == 0) ? 1 : 0);
  }

  token_logits_kernel<<<M_ / 8, 512, 0, stream>>>(X, wp_g, wp_b, wp_w, wp_bias, tlog);
  route_pool_kernel<<<B_ * R_, 256, 0, stream>>>(X, tlog, route_ids, maskN, routes, present);
  final_pool_kernel<<<B_, 512, 0, stream>>>(routes, present, rp_g, rp_b, rp_w, rp_bias, out);
}

// Round 2
// 429.201 us; speedup vs baseline: 1.1254x; 1.1254x over previous
//
#include <hip/hip_runtime.h>
#include <hip/hip_bf16.h>
#include <math.h>

// Problem constants (B=64, N=512, D=512, H=4D=2048, R=32 routes)
#define B_ 64
#define N_ 512
#define D_ 512
#define H_ 2048
#define R_ 32
#define M_ (B_ * N_)  // 32768 token rows

typedef __bf16 bf16x8 __attribute__((ext_vector_type(8)));
typedef float f32x4 __attribute__((ext_vector_type(4)));

__device__ __forceinline__ void async_ld16(const void* g, void* l) {
  __builtin_amdgcn_global_load_lds((__attribute__((address_space(1))) void*)g,
                                   (__attribute__((address_space(3))) void*)l,
                                   16, 0, 0);
}

// Abramowitz-Stegun 7.1.26 erf (max err 1.5e-7): 1 exp + 1 div + ~10 fma.
// Replaces erff libcall (branchy, ~50 ops) that made gemm1 62% VALUBusy.
__device__ __forceinline__ float fast_gelu(float v) {
  const float s = v * 0.70710678118654752f;
  const float a = fabsf(s);
  const float t = 1.0f / fmaf(0.3275911f, a, 1.0f);
  const float poly = t * fmaf(t, fmaf(t, fmaf(t, fmaf(t, 1.061405429f, -1.453152027f),
                                              1.421413741f), -0.284496736f), 0.254829592f);
  const float er = 1.0f - poly * __expf(-a * a);
  const float erfs = (s >= 0.f) ? er : -er;
  return 0.5f * v * (1.0f + erfs);
}

// ---------------------------------------------------------------------------
// mask dtype detect (bool may arrive as int32 or raw bytes). Vectorized:
// any nonzero byte at offset % 4 != 0  =>  byte format.
// ---------------------------------------------------------------------------
__global__ void mask_detect_kernel(const unsigned char* __restrict__ raw,
                                   int* __restrict__ flag) {
  __shared__ int f;
  if (threadIdx.x == 0) f = 0;
  __syncthreads();
  const uint4* p = (const uint4*)raw;
  unsigned acc = 0;
  for (int k = threadIdx.x; k < M_ / 16; k += 256) {
    const uint4 v = p[k];
    acc |= (v.x | v.y | v.z | v.w) & 0xFFFFFF00u;
  }
  if (acc) f = 1;  // benign race
  __syncthreads();
  if (threadIdx.x == 0) flag[0] = f;
}

// ---------------------------------------------------------------------------
// Transpose + cast f32 [R,C] -> bf16 [C,R]
// ---------------------------------------------------------------------------
__global__ __launch_bounds__(256) void transpose_cast_kernel(
    const float* __restrict__ src, __hip_bfloat16* __restrict__ dst, int R, int C) {
  __shared__ float tile[64][65];
  const int c0 = blockIdx.x * 64, r0 = blockIdx.y * 64;
  const int tx = threadIdx.x & 63, ty = threadIdx.x >> 6;
  for (int r = ty; r < 64; r += 4)
    tile[r][tx] = src[(size_t)(r0 + r) * C + c0 + tx];
  __syncthreads();
  for (int r = ty; r < 64; r += 4)
    dst[(size_t)(c0 + r) * R + r0 + tx] = __float2bfloat16(tile[tx][r]);
}

// ---------------------------------------------------------------------------
// LayerNorm rows -> bf16 (one wave per 512-elem row)
// ---------------------------------------------------------------------------
__global__ __launch_bounds__(512) void ln_rows_kernel(
    const float* __restrict__ src, const float* __restrict__ gw,
    const float* __restrict__ gb, __hip_bfloat16* __restrict__ dst) {
  const int wv = threadIdx.x >> 6, lane = threadIdx.x & 63;
  const int row = blockIdx.x * 8 + wv;
  const float* p = src + (size_t)row * D_ + lane * 8;
  const float4 v0 = *(const float4*)p;
  const float4 v1 = *(const float4*)(p + 4);
  float s = v0.x + v0.y + v0.z + v0.w + v1.x + v1.y + v1.z + v1.w;
  float ss = v0.x * v0.x + v0.y * v0.y + v0.z * v0.z + v0.w * v0.w +
             v1.x * v1.x + v1.y * v1.y + v1.z * v1.z + v1.w * v1.w;
#pragma unroll
  for (int m = 32; m > 0; m >>= 1) {
    s += __shfl_xor(s, m);
    ss += __shfl_xor(ss, m);
  }
  const float mu = s * (1.0f / D_);
  const float rstd = rsqrtf(ss * (1.0f / D_) - mu * mu + 1e-5f);
  const float4 g0 = *(const float4*)(gw + lane * 8);
  const float4 g1 = *(const float4*)(gw + lane * 8 + 4);
  const float4 b0 = *(const float4*)(gb + lane * 8);
  const float4 b1 = *(const float4*)(gb + lane * 8 + 4);
  const float vv[8] = {v0.x, v0.y, v0.z, v0.w, v1.x, v1.y, v1.z, v1.w};
  const float gg[8] = {g0.x, g0.y, g0.z, g0.w, g1.x, g1.y, g1.z, g1.w};
  const float bb[8] = {b0.x, b0.y, b0.z, b0.w, b1.x, b1.y, b1.z, b1.w};
  union { __hip_bfloat16 h[8]; uint4 u; } pk;
#pragma unroll
  for (int t = 0; t < 8; ++t)
    pk.h[t] = __float2bfloat16((vv[t] - mu) * rstd * gg[t] + bb[t]);
  *(uint4*)(dst + (size_t)row * D_ + lane * 8) = pk.u;
}

// ---------------------------------------------------------------------------
// GEMM1: C = gelu(A @ Bt^T + bias). 128x128 tile, BK=32, 16x16x32 MFMA.
// LDS k-slot XOR-swizzle (kills 8-way bank conflicts); supertile grid swizzle
// (same-row col-tiles -> same XCD); LDS-restaged coalesced bf16 C-store.
// ---------------------------------------------------------------------------
__global__ __launch_bounds__(256, 2) void gemm_bias_gelu_kernel(
    const __hip_bfloat16* __restrict__ A, const __hip_bfloat16* __restrict__ Bt,
    const float* __restrict__ bias, __hip_bfloat16* __restrict__ C,
    int K, int ldc, int NC) {
  __shared__ alignas(16) unsigned short SU[8192];  // As[0:4096] | Bs[4096:8192]
  unsigned short* As = SU;
  unsigned short* Bs = SU + 4096;
  const int tid = threadIdx.x;
  const int w = tid >> 6;
  const int lane = tid & 63;
  const int bid = blockIdx.x;
  const int rowT = (bid / (NC * 8)) * 8 + (bid & 7);
  const int colT = (bid >> 3) % NC;
  const int rowBase = rowT * 128;
  const int colBase = colT * 128;
  const int warpRow = w >> 1;
  const int warpCol = w & 1;
  const int q = lane >> 4;
  const int mr = lane & 15;
  const int srow = lane >> 2;
  const int skc = (((lane & 3) ^ ((srow >> 1) & 3))) * 8;  // swizzled k-chunk
  const int jsA = q ^ ((mr >> 1) & 3);                     // fragment k-slot

  f32x4 acc[4][4] = {};

  for (int k0 = 0; k0 < K; k0 += 32) {
    __syncthreads();
#pragma unroll
    for (int i = 0; i < 2; ++i) {
      const int c = i * 4 + w;
      const int row = c * 16 + srow;
      async_ld16(&A[(size_t)(rowBase + row) * K + (k0 + skc)], (void*)&As[c * 512]);
      async_ld16(&Bt[(size_t)(colBase + row) * K + (k0 + skc)], (void*)&Bs[c * 512]);
    }
    __syncthreads();
    bf16x8 af[4], bf[4];
#pragma unroll
    for (int i = 0; i < 4; ++i)
      af[i] = *reinterpret_cast<const bf16x8*>(&As[(warpRow * 64 + i * 16 + mr) * 32 + jsA * 8]);
#pragma unroll
    for (int j = 0; j < 4; ++j)
      bf[j] = *reinterpret_cast<const bf16x8*>(&Bs[(warpCol * 64 + j * 16 + mr) * 32 + jsA * 8]);
#pragma unroll
    for (int i = 0; i < 4; ++i)
#pragma unroll
      for (int j = 0; j < 4; ++j)
        acc[i][j] = __builtin_amdgcn_mfma_f32_16x16x32_bf16(af[i], bf[j], acc[i][j], 0, 0, 0);
  }

  // epilogue: restage through LDS (2 slabs of 64x128 bf16 = 16 KB each pass)
  __hip_bfloat16* SB = (__hip_bfloat16*)SU;
  const int lg = tid & 15;   // half-group of 8 cols
  const int rsub = tid >> 4; // row within 16-row slab
#pragma unroll
  for (int p = 0; p < 2; ++p) {
    __syncthreads();
    if (warpRow == p) {
#pragma unroll
      for (int j = 0; j < 4; ++j) {
        const int n = warpCol * 64 + j * 16 + mr;
        const float bv = bias[colBase + n];
        const int g16 = n >> 4;
#pragma unroll
        for (int i = 0; i < 4; ++i) {
#pragma unroll
          for (int r = 0; r < 4; ++r) {
            const int m = i * 16 + q * 4 + r;  // 0..63
            SB[m * 128 + ((g16 ^ (m & 7)) << 4) + (n & 15)] =
                __float2bfloat16(fast_gelu(acc[i][j][r] + bv));
          }
        }
      }
    }
    __syncthreads();
#pragma unroll
    for (int it = 0; it < 4; ++it) {
      const int m = it * 16 + rsub;
      const int pg = (lg >> 1) ^ (m & 7);
      const uint4 val = *(const uint4*)&SB[m * 128 + (pg << 4) + (lg & 1) * 8];
      *(uint4*)&C[(size_t)(rowBase + p * 64 + m) * ldc + colBase + lg * 8] = val;
    }
  }
}

// ---------------------------------------------------------------------------
// GEMM2: X = (first ? resid + bias : X) + A @ Bt^T  (fp32 out w/ residual)
// ---------------------------------------------------------------------------
__global__ __launch_bounds__(256, 2) void gemm_acc_kernel(
    const __hip_bfloat16* __restrict__ A, const __hip_bfloat16* __restrict__ Bt,
    const float* __restrict__ bias, const float* __restrict__ resid,
    float* __restrict__ X, int K, int ldb, int first) {
  __shared__ alignas(16) unsigned short SU[8192];
  unsigned short* As = SU;
  unsigned short* Bs = SU + 4096;
  const int tid = threadIdx.x;
  const int w = tid >> 6;
  const int lane = tid & 63;
  const int bid = blockIdx.x;
  const int NC = 4;  // 512/128
  const int rowT = (bid / (NC * 8)) * 8 + (bid & 7);
  const int colT = (bid >> 3) % NC;
  const int rowBase = rowT * 128;
  const int colBase = colT * 128;
  const int warpRow = w >> 1;
  const int warpCol = w & 1;
  const int q = lane >> 4;
  const int mr = lane & 15;
  const int srow = lane >> 2;
  const int skc = (((lane & 3) ^ ((srow >> 1) & 3))) * 8;
  const int jsA = q ^ ((mr >> 1) & 3);

  f32x4 acc[4][4] = {};

  for (int k0 = 0; k0 < K; k0 += 32) {
    __syncthreads();
#pragma unroll
    for (int i = 0; i < 2; ++i) {
      const int c = i * 4 + w;
      const int row = c * 16 + srow;
      async_ld16(&A[(size_t)(rowBase + row) * K + (k0 + skc)], (void*)&As[c * 512]);
      async_ld16(&Bt[(size_t)(colBase + row) * ldb + (k0 + skc)], (void*)&Bs[c * 512]);
    }
    __syncthreads();
    bf16x8 af[4], bf[4];
#pragma unroll
    for (int i = 0; i < 4; ++i)
      af[i] = *reinterpret_cast<const bf16x8*>(&As[(warpRow * 64 + i * 16 + mr) * 32 + jsA * 8]);
#pragma unroll
    for (int j = 0; j < 4; ++j)
      bf[j] = *reinterpret_cast<const bf16x8*>(&Bs[(warpCol * 64 + j * 16 + mr) * 32 + jsA * 8]);
#pragma unroll
    for (int i = 0; i < 4; ++i)
#pragma unroll
      for (int j = 0; j < 4; ++j)
        acc[i][j] = __builtin_amdgcn_mfma_f32_16x16x32_bf16(af[i], bf[j], acc[i][j], 0, 0, 0);
  }

#pragma unroll
  for (int j = 0; j < 4; ++j) {
    const int n = colBase + warpCol * 64 + j * 16 + mr;
    const float bv = bias[n];
#pragma unroll
    for (int i = 0; i < 4; ++i) {
#pragma unroll
      for (int r = 0; r < 4; ++r) {
        const int m = rowBase + warpRow * 64 + i * 16 + q * 4 + r;
        const size_t idx = (size_t)m * N_ + n;  // X is [M, D_=512]
        const float base = first ? (resid[idx] + bv) : X[idx];
        X[idx] = base + acc[i][j][r];
      }
    }
  }
}

// ---------------------------------------------------------------------------
// Fused per-(b,route) pool: select tokens, compute LN+dot logits (each token
// belongs to exactly one route), masked softmax, weighted sum -> routes.
// ---------------------------------------------------------------------------
__global__ __launch_bounds__(256) void route_pool_kernel(
    const float* __restrict__ X, const int* __restrict__ route_ids,
    const void* __restrict__ mask_raw, const int* __restrict__ flag,
    const float* __restrict__ gw, const float* __restrict__ gb,
    const float* __restrict__ ww, const float* __restrict__ wbias,
    float* __restrict__ routes, int* __restrict__ present) {
  const int b = blockIdx.x >> 5;
  const int r = blockIdx.x & 31;
  const int tid = threadIdx.x;
  __shared__ int cnt;
  __shared__ int ls[N_];
  __shared__ float lw[N_];
  if (tid == 0) cnt = 0;
  __syncthreads();
  const int fl = flag[0];
  for (int n = tid; n < N_; n += 256) {
    const int mk = fl ? (int)((const unsigned char*)mask_raw)[b * N_ + n]
                      : ((const int*)mask_raw)[b * N_ + n];
    if (route_ids[n] == r && mk != 0) {
      int p = atomicAdd(&cnt, 1);
      ls[p] = n;
    }
  }
  __syncthreads();
  const int c = cnt;
  // logits: one wave per selected token (LN + dot over 512)
  const int wv = tid >> 6, lane = tid & 63;
  for (int t = wv; t < c; t += 4) {
    const float* p = X + ((size_t)b * N_ + ls[t]) * D_ + lane * 8;
    const float4 v0 = *(const float4*)p;
    const float4 v1 = *(const float4*)(p + 4);
    float s = v0.x + v0.y + v0.z + v0.w + v1.x + v1.y + v1.z + v1.w;
    float ss = v0.x * v0.x + v0.y * v0.y + v0.z * v0.z + v0.w * v0.w +
               v1.x * v1.x + v1.y * v1.y + v1.z * v1.z + v1.w * v1.w;
#pragma unroll
    for (int m = 32; m > 0; m >>= 1) {
      s += __shfl_xor(s, m);
      ss += __shfl_xor(ss, m);
    }
    const float mu = s * (1.0f / D_);
    const float rstd = rsqrtf(ss * (1.0f / D_) - mu * mu + 1e-5f);
    const float4 g0 = *(const float4*)(gw + lane * 8);
    const float4 g1 = *(const float4*)(gw + lane * 8 + 4);
    const float4 b0 = *(const float4*)(gb + lane * 8);
    const float4 b1 = *(const float4*)(gb + lane * 8 + 4);
    const float4 w0 = *(const float4*)(ww + lane * 8);
    const float4 w1 = *(const float4*)(ww + lane * 8 + 4);
    const float vv[8] = {v0.x, v0.y, v0.z, v0.w, v1.x, v1.y, v1.z, v1.w};
    const float gg[8] = {g0.x, g0.y, g0.z, g0.w, g1.x, g1.y, g1.z, g1.w};
    const float bb[8] = {b0.x, b0.y, b0.z, b0.w, b1.x, b1.y, b1.z, b1.w};
    const float wwv[8] = {w0.x, w0.y, w0.z, w0.w, w1.x, w1.y, w1.z, w1.w};
    float a = 0.f;
#pragma unroll
    for (int t2 = 0; t2 < 8; ++t2) a += ((vv[t2] - mu) * rstd * gg[t2] + bb[t2]) * wwv[t2];
#pragma unroll
    for (int m = 32; m > 0; m >>= 1) a += __shfl_xor(a, m);
    if (lane == 0) lw[t] = a + wbias[0];
  }
  __syncthreads();
  if (tid == 0 && c > 0) {
    float mx = -1e30f;
    for (int i = 0; i < c; ++i) mx = fmaxf(mx, lw[i]);
    float sm = 0.f;
    for (int i = 0; i < c; ++i) {
      const float e = __expf(lw[i] - mx);
      lw[i] = e;
      sm += e;
    }
    const float inv = 1.0f / sm;
    for (int i = 0; i < c; ++i) lw[i] *= inv;
  }
  __syncthreads();
  float a0 = 0.f, a1 = 0.f;
  for (int i = 0; i < c; ++i) {
    const float* xr = X + ((size_t)b * N_ + ls[i]) * D_;
    const float wgt = lw[i];
    a0 += wgt * xr[tid];
    a1 += wgt * xr[tid + 256];
  }
  float* outp = routes + ((size_t)b * R_ + r) * D_;
  outp[tid] = a0;
  outp[tid + 256] = a1;
  if (tid == 0) present[b * R_ + r] = (c > 0) ? 1 : 0;
}

// ---------------------------------------------------------------------------
// Final pool over routes (one block of 512 per batch)
// ---------------------------------------------------------------------------
__global__ __launch_bounds__(512) void final_pool_kernel(
    const float* __restrict__ routes, const int* __restrict__ present,
    const float* __restrict__ gw, const float* __restrict__ gb,
    const float* __restrict__ ww, const float* __restrict__ wbias,
    float* __restrict__ out) {
  const int b = blockIdx.x;
  const int wv = threadIdx.x >> 6, lane = threadIdx.x & 63;
  __shared__ float srw[R_];
  __shared__ float srl[R_];
  for (int r = wv; r < R_; r += 8) {
    const float* p = routes + ((size_t)b * R_ + r) * D_ + lane * 8;
    const float4 v0 = *(const float4*)p;
    const float4 v1 = *(const float4*)(p + 4);
    float s = v0.x + v0.y + v0.z + v0.w + v1.x + v1.y + v1.z + v1.w;
    float ss = v0.x * v0.x + v0.y * v0.y + v0.z * v0.z + v0.w * v0.w +
               v1.x * v1.x + v1.y * v1.y + v1.z * v1.z + v1.w * v1.w;
#pragma unroll
    for (int m = 32; m > 0; m >>= 1) {
      s += __shfl_xor(s, m);
      ss += __shfl_xor(ss, m);
    }
    const float mu = s * (1.0f / D_);
    const float rstd = rsqrtf(ss * (1.0f / D_) - mu * mu + 1e-5f);
    const float4 g0 = *(const float4*)(gw + lane * 8);
    const float4 g1 = *(const float4*)(gw + lane * 8 + 4);
    const float4 b0 = *(const float4*)(gb + lane * 8);
    const float4 b1 = *(const float4*)(gb + lane * 8 + 4);
    const float4 w0 = *(const float4*)(ww + lane * 8);
    const float4 w1 = *(const float4*)(ww + lane * 8 + 4);
    const float vv[8] = {v0.x, v0.y, v0.z, v0.w, v1.x, v1.y, v1.z, v1.w};
    const float gg[8] = {g0.x, g0.y, g0.z, g0.w, g1.x, g1.y, g1.z, g1.w};
    const float bb[8] = {b0.x, b0.y, b0.z, b0.w, b1.x, b1.y, b1.z, b1.w};
    const float wwv[8] = {w0.x, w0.y, w0.z, w0.w, w1.x, w1.y, w1.z, w1.w};
    float a = 0.f;
#pragma unroll
    for (int t = 0; t < 8; ++t) a += ((vv[t] - mu) * rstd * gg[t] + bb[t]) * wwv[t];
#pragma unroll
    for (int m = 32; m > 0; m >>= 1) a += __shfl_xor(a, m);
    if (lane == 0) srl[r] = a + wbias[0];
  }
  __syncthreads();
  if (threadIdx.x == 0) {
    float mx = -1e30f;
    for (int r = 0; r < R_; ++r)
      if (present[b * R_ + r]) mx = fmaxf(mx, srl[r]);
    float sm = 0.f;
    for (int r = 0; r < R_; ++r) {
      const float e = present[b * R_ + r] ? __expf(srl[r] - mx) : 0.f;
      srw[r] = e;
      sm += e;
    }
    const float inv = (sm > 0.f) ? 1.0f / sm : 0.f;
    for (int r = 0; r < R_; ++r) srw[r] *= inv;
  }
  __syncthreads();
  const int d = threadIdx.x;
  float a = 0.f;
  for (int r = 0; r < R_; ++r) a += srw[r] * routes[((size_t)b * R_ + r) * D_ + d];
  out[(size_t)b * D_ + d] = a;
}

// ---------------------------------------------------------------------------
extern "C" void kernel_launch(void* const* d_in, const int* in_sizes, int n_in,
                              void* d_out, int out_size, void* d_ws, size_t ws_size,
                              hipStream_t stream) {
  const float* tokens = (const float*)d_in[0];
  const void* mask_raw = d_in[1];
  const int* route_ids = (const int*)d_in[2];
  const float* ln1_g = (const float*)d_in[3];
  const float* ln1_b = (const float*)d_in[4];
  const float* w1 = (const float*)d_in[5];
  const float* b1 = (const float*)d_in[6];
  const float* w2 = (const float*)d_in[7];
  const float* b2 = (const float*)d_in[8];
  const float* wp_g = (const float*)d_in[9];
  const float* wp_b = (const float*)d_in[10];
  const float* wp_w = (const float*)d_in[11];
  const float* wp_bias = (const float*)d_in[12];
  const float* rp_g = (const float*)d_in[13];
  const float* rp_b = (const float*)d_in[14];
  const float* rp_w = (const float*)d_in[15];
  const float* rp_bias = (const float*)d_in[16];
  float* out = (float*)d_out;

  char* ws = (char*)d_ws;
  size_t off = 0;
  auto carve = [&](size_t bytes) -> void* {
    void* p = ws + off;
    off = (off + bytes + 255) & ~(size_t)255;
    return p;
  };

  __hip_bfloat16* w1t = (__hip_bfloat16*)carve((size_t)H_ * D_ * 2);  // [H, D]
  __hip_bfloat16* w2t = (__hip_bfloat16*)carve((size_t)D_ * H_ * 2);  // [D, H]
  __hip_bfloat16* aBf = (__hip_bfloat16*)carve((size_t)M_ * D_ * 2);  // LN1 out
  float* X = (float*)carve((size_t)M_ * D_ * 4);                      // FFN out
  int* flag = (int*)carve(256);
  int* present = (int*)carve((size_t)B_ * R_ * 4);
  float* routes = (float*)carve((size_t)B_ * R_ * D_ * 4);

  int G = 1;
  while (G < 16 && off + (size_t)M_ * (H_ / G) * 2 > ws_size) G <<= 1;
  const int Hg = H_ / G;
  __hip_bfloat16* hbuf = (__hip_bfloat16*)carve((size_t)M_ * Hg * 2);

  mask_detect_kernel<<<1, 256, 0, stream>>>((const unsigned char*)mask_raw, flag);
  transpose_cast_kernel<<<dim3(H_ / 64, D_ / 64), 256, 0, stream>>>(w1, w1t, D_, H_);
  transpose_cast_kernel<<<dim3(D_ / 64, H_ / 64), 256, 0, stream>>>(w2, w2t, H_, D_);
  ln_rows_kernel<<<M_ / 8, 512, 0, stream>>>(tokens, ln1_g, ln1_b, aBf);

  const int NC1 = Hg / 128;
  for (int g = 0; g < G; ++g) {
    gemm_bias_gelu_kernel<<<(M_ / 128) * NC1, 256, 0, stream>>>(
        aBf, w1t + (size_t)g * Hg * D_, b1 + (size_t)g * Hg, hbuf, D_, Hg, NC1);
    gemm_acc_kernel<<<(M_ / 128) * 4, 256, 0, stream>>>(
        hbuf, w2t + (size_t)g * Hg, b2, tokens, X, Hg, H_, (g == 0) ? 1 : 0);
  }

  route_pool_kernel<<<B_ * R_, 256, 0, stream>>>(
      X, route_ids, mask_raw, flag, wp_g, wp_b, wp_w, wp_bias, routes, present);
  final_pool_kernel<<<B_, 512, 0, stream>>>(routes, present, rp_g, rp_b, rp_w, rp_bias, out);
}

// Round 3
// 422.077 us; speedup vs baseline: 1.1444x; 1.0169x over previous
//
#include <hip/hip_runtime.h>
#include <hip/hip_bf16.h>
#include <math.h>

// Problem constants (B=64, N=512, D=512, H=4D=2048, R=32 routes)
#define B_ 64
#define N_ 512
#define D_ 512
#define H_ 2048
#define R_ 32
#define M_ (B_ * N_)  // 32768 token rows

typedef __bf16 bf16x8 __attribute__((ext_vector_type(8)));
typedef float f32x4 __attribute__((ext_vector_type(4)));

__device__ __forceinline__ void async_ld16(const void* g, void* l) {
  __builtin_amdgcn_global_load_lds((__attribute__((address_space(1))) void*)g,
                                   (__attribute__((address_space(3))) void*)l,
                                   16, 0, 0);
}

// Abramowitz-Stegun 7.1.26 erf (max err 1.5e-7): 1 exp + 1 div + ~10 fma.
__device__ __forceinline__ float fast_gelu(float v) {
  const float s = v * 0.70710678118654752f;
  const float a = fabsf(s);
  const float t = 1.0f / fmaf(0.3275911f, a, 1.0f);
  const float poly = t * fmaf(t, fmaf(t, fmaf(t, fmaf(t, 1.061405429f, -1.453152027f),
                                              1.421413741f), -0.284496736f), 0.254829592f);
  const float er = 1.0f - poly * __expf(-a * a);
  const float erfs = (s >= 0.f) ? er : -er;
  return 0.5f * v * (1.0f + erfs);
}

// ---------------------------------------------------------------------------
// mask dtype detect (bool may arrive as int32 or raw bytes)
// ---------------------------------------------------------------------------
__global__ void mask_detect_kernel(const unsigned char* __restrict__ raw,
                                   int* __restrict__ flag) {
  __shared__ int f;
  if (threadIdx.x == 0) f = 0;
  __syncthreads();
  const uint4* p = (const uint4*)raw;
  unsigned acc = 0;
  for (int k = threadIdx.x; k < M_ / 16; k += 256) {
    const uint4 v = p[k];
    acc |= (v.x | v.y | v.z | v.w) & 0xFFFFFF00u;
  }
  if (acc) f = 1;  // benign race
  __syncthreads();
  if (threadIdx.x == 0) flag[0] = f;
}

// ---------------------------------------------------------------------------
// Transpose + cast f32 [R,C] -> bf16 [C,R]
// ---------------------------------------------------------------------------
__global__ __launch_bounds__(256) void transpose_cast_kernel(
    const float* __restrict__ src, __hip_bfloat16* __restrict__ dst, int R, int C) {
  __shared__ float tile[64][65];
  const int c0 = blockIdx.x * 64, r0 = blockIdx.y * 64;
  const int tx = threadIdx.x & 63, ty = threadIdx.x >> 6;
  for (int r = ty; r < 64; r += 4)
    tile[r][tx] = src[(size_t)(r0 + r) * C + c0 + tx];
  __syncthreads();
  for (int r = ty; r < 64; r += 4)
    dst[(size_t)(c0 + r) * R + r0 + tx] = __float2bfloat16(tile[tx][r]);
}

// ---------------------------------------------------------------------------
// LayerNorm rows -> bf16 (one wave per 512-elem row)
// ---------------------------------------------------------------------------
__global__ __launch_bounds__(512) void ln_rows_kernel(
    const float* __restrict__ src, const float* __restrict__ gw,
    const float* __restrict__ gb, __hip_bfloat16* __restrict__ dst) {
  const int wv = threadIdx.x >> 6, lane = threadIdx.x & 63;
  const int row = blockIdx.x * 8 + wv;
  const float* p = src + (size_t)row * D_ + lane * 8;
  const float4 v0 = *(const float4*)p;
  const float4 v1 = *(const float4*)(p + 4);
  float s = v0.x + v0.y + v0.z + v0.w + v1.x + v1.y + v1.z + v1.w;
  float ss = v0.x * v0.x + v0.y * v0.y + v0.z * v0.z + v0.w * v0.w +
             v1.x * v1.x + v1.y * v1.y + v1.z * v1.z + v1.w * v1.w;
#pragma unroll
  for (int m = 32; m > 0; m >>= 1) {
    s += __shfl_xor(s, m);
    ss += __shfl_xor(ss, m);
  }
  const float mu = s * (1.0f / D_);
  const float rstd = rsqrtf(ss * (1.0f / D_) - mu * mu + 1e-5f);
  const float4 g0 = *(const float4*)(gw + lane * 8);
  const float4 g1 = *(const float4*)(gw + lane * 8 + 4);
  const float4 b0 = *(const float4*)(gb + lane * 8);
  const float4 b1 = *(const float4*)(gb + lane * 8 + 4);
  const float vv[8] = {v0.x, v0.y, v0.z, v0.w, v1.x, v1.y, v1.z, v1.w};
  const float gg[8] = {g0.x, g0.y, g0.z, g0.w, g1.x, g1.y, g1.z, g1.w};
  const float bb[8] = {b0.x, b0.y, b0.z, b0.w, b1.x, b1.y, b1.z, b1.w};
  union { __hip_bfloat16 h[8]; uint4 u; } pk;
#pragma unroll
  for (int t = 0; t < 8; ++t)
    pk.h[t] = __float2bfloat16((vv[t] - mu) * rstd * gg[t] + bb[t]);
  *(uint4*)(dst + (size_t)row * D_ + lane * 8) = pk.u;
}

// ---------------------------------------------------------------------------
// FUSED FFN: X = resid + b2 + gelu(A @ W1 + b1) @ W2
// Block = 512 threads (8 waves), 128 token rows. A resident in LDS
// (128 x 520 bf16, +4 pad elems/row -> conflict-free ds_read_b128).
// Loop 32 h-chunks of 64 cols: Hc in regs -> swizzled LDS restage
// (C-layout -> A-layout) -> X += Hc @ W2 into persistent 128-VGPR acc.
// LDS: 128*520*2 + 128*64*2 = 149504 B (needs >64KB workgroup LDS; gated
// at runtime, falls back to the 2-GEMM pipeline below).
// ---------------------------------------------------------------------------
#define ASTRIDE 520
#define FUSED_LDS ((128 * ASTRIDE + 128 * 64) * 2)

__global__ __launch_bounds__(512, 2) void ffn_fused_kernel(
    const __hip_bfloat16* __restrict__ aBf,   // [M,512] LN'd tokens
    const __hip_bfloat16* __restrict__ w1t,   // [2048,512]
    const __hip_bfloat16* __restrict__ w2t,   // [512,2048]
    const float* __restrict__ b1,             // [2048]
    const float* __restrict__ b2,             // [512]
    const float* __restrict__ resid,          // [M,512] tokens
    float* __restrict__ X) {                  // [M,512]
  extern __shared__ unsigned short smem[];
  unsigned short* Als = smem;                    // 128 x 520
  unsigned short* Hls = smem + 128 * ASTRIDE;    // 128 x 64, slot-swizzled
  const int tid = threadIdx.x;
  const int w = tid >> 6;          // 0..7
  const int lane = tid & 63;
  const int q = lane >> 4, mr = lane & 15;
  const int rowBase = blockIdx.x * 128;
  const int hr = w >> 2;           // 0..1 : row half (used by both phases)
  const int hc = w & 3;            // 0..3 : col group (used by both phases)

  // --- stage A: one 1KB row per wave-iteration, contiguous, 16B/lane ---
  {
    const __hip_bfloat16* src = aBf + (size_t)rowBase * 512;
#pragma unroll
    for (int rr = 0; rr < 16; ++rr) {
      const int row = w * 16 + rr;
      async_ld16(src + (size_t)row * 512 + lane * 8, (void*)&Als[row * ASTRIDE]);
    }
  }
  f32x4 accX[4][8] = {};
  __syncthreads();

  for (int ch = 0; ch < 32; ++ch) {
    const int cb = ch * 64;
    // --- Hc = A @ W1 for cols [cb+hc*16, +16), rows [hr*64, +64) ---
    f32x4 accH[4] = {};
    const __hip_bfloat16* w1p = w1t + (size_t)(cb + hc * 16 + mr) * 512 + q * 8;
#pragma unroll
    for (int s = 0; s < 16; ++s) {
      const bf16x8 bw = *(const bf16x8*)(w1p + s * 32);
#pragma unroll
      for (int i = 0; i < 4; ++i) {
        const bf16x8 af =
            *(const bf16x8*)&Als[(hr * 64 + i * 16 + mr) * ASTRIDE + s * 32 + q * 8];
        accH[i] = __builtin_amdgcn_mfma_f32_16x16x32_bf16(af, bw, accH[i], 0, 0, 0);
      }
    }
    // bias + gelu -> Hls (b16 scattered, slot XOR (row&7) kills read conflicts)
    const float bv = b1[cb + hc * 16 + mr];
    __syncthreads();  // prev chunk's Hls reads complete
#pragma unroll
    for (int i = 0; i < 4; ++i) {
#pragma unroll
      for (int r = 0; r < 4; ++r) {
        const int row = hr * 64 + i * 16 + q * 4 + r;
        const int col = hc * 16 + mr;
        const int slot = (col >> 3) ^ (row & 7);
        const __hip_bfloat16 hv = __float2bfloat16(fast_gelu(accH[i][r] + bv));
        Hls[row * 64 + slot * 8 + (col & 7)] = *(const unsigned short*)&hv;
      }
    }
    __syncthreads();  // Hls visible
    // --- X += Hc @ W2 over k in [cb, cb+64); wave: rows [hr*64,+64) x cols [hc*128,+128)
    const __hip_bfloat16* w2p = w2t + (size_t)(hc * 128 + mr) * 2048 + cb + q * 8;
#pragma unroll
    for (int s = 0; s < 2; ++s) {
      bf16x8 aH[4];
#pragma unroll
      for (int i = 0; i < 4; ++i) {
        const int row = hr * 64 + i * 16 + mr;
        const int slot = (s * 4 + q) ^ (mr & 7);
        aH[i] = *(const bf16x8*)&Hls[row * 64 + slot * 8];
      }
#pragma unroll
      for (int j = 0; j < 8; ++j) {
        const bf16x8 bw2 = *(const bf16x8*)(w2p + (size_t)(j * 16) * 2048 + s * 32);
#pragma unroll
        for (int i = 0; i < 4; ++i)
          accX[i][j] = __builtin_amdgcn_mfma_f32_16x16x32_bf16(aH[i], bw2, accX[i][j], 0, 0, 0);
      }
    }
  }

  // epilogue: X = resid + b2 + accX (f32 dword stores, 4 full 64B lines/instr)
#pragma unroll
  for (int j = 0; j < 8; ++j) {
    const int n = hc * 128 + j * 16 + mr;
    const float bvo = b2[n];
#pragma unroll
    for (int i = 0; i < 4; ++i) {
#pragma unroll
      for (int r = 0; r < 4; ++r) {
        const int m = rowBase + hr * 64 + i * 16 + q * 4 + r;
        const size_t idx = (size_t)m * 512 + n;
        X[idx] = resid[idx] + bvo + accX[i][j][r];
      }
    }
  }
}

// ---------------------------------------------------------------------------
// FALLBACK PATH (R2 pipeline, unchanged): gemm1 + gemm2 via hbuf
// ---------------------------------------------------------------------------
__global__ __launch_bounds__(256, 2) void gemm_bias_gelu_kernel(
    const __hip_bfloat16* __restrict__ A, const __hip_bfloat16* __restrict__ Bt,
    const float* __restrict__ bias, __hip_bfloat16* __restrict__ C,
    int K, int ldc, int NC) {
  __shared__ alignas(16) unsigned short SU[8192];
  unsigned short* As = SU;
  unsigned short* Bs = SU + 4096;
  const int tid = threadIdx.x;
  const int w = tid >> 6;
  const int lane = tid & 63;
  const int bid = blockIdx.x;
  const int rowT = (bid / (NC * 8)) * 8 + (bid & 7);
  const int colT = (bid >> 3) % NC;
  const int rowBase = rowT * 128;
  const int colBase = colT * 128;
  const int warpRow = w >> 1;
  const int warpCol = w & 1;
  const int q = lane >> 4;
  const int mr = lane & 15;
  const int srow = lane >> 2;
  const int skc = (((lane & 3) ^ ((srow >> 1) & 3))) * 8;
  const int jsA = q ^ ((mr >> 1) & 3);

  f32x4 acc[4][4] = {};

  for (int k0 = 0; k0 < K; k0 += 32) {
    __syncthreads();
#pragma unroll
    for (int i = 0; i < 2; ++i) {
      const int c = i * 4 + w;
      const int row = c * 16 + srow;
      async_ld16(&A[(size_t)(rowBase + row) * K + (k0 + skc)], (void*)&As[c * 512]);
      async_ld16(&Bt[(size_t)(colBase + row) * K + (k0 + skc)], (void*)&Bs[c * 512]);
    }
    __syncthreads();
    bf16x8 af[4], bf[4];
#pragma unroll
    for (int i = 0; i < 4; ++i)
      af[i] = *reinterpret_cast<const bf16x8*>(&As[(warpRow * 64 + i * 16 + mr) * 32 + jsA * 8]);
#pragma unroll
    for (int j = 0; j < 4; ++j)
      bf[j] = *reinterpret_cast<const bf16x8*>(&Bs[(warpCol * 64 + j * 16 + mr) * 32 + jsA * 8]);
#pragma unroll
    for (int i = 0; i < 4; ++i)
#pragma unroll
      for (int j = 0; j < 4; ++j)
        acc[i][j] = __builtin_amdgcn_mfma_f32_16x16x32_bf16(af[i], bf[j], acc[i][j], 0, 0, 0);
  }

  __hip_bfloat16* SB = (__hip_bfloat16*)SU;
  const int lg = tid & 15;
  const int rsub = tid >> 4;
#pragma unroll
  for (int p = 0; p < 2; ++p) {
    __syncthreads();
    if (warpRow == p) {
#pragma unroll
      for (int j = 0; j < 4; ++j) {
        const int n = warpCol * 64 + j * 16 + mr;
        const float bv = bias[colBase + n];
        const int g16 = n >> 4;
#pragma unroll
        for (int i = 0; i < 4; ++i) {
#pragma unroll
          for (int r = 0; r < 4; ++r) {
            const int m = i * 16 + q * 4 + r;
            SB[m * 128 + ((g16 ^ (m & 7)) << 4) + (n & 15)] =
                __float2bfloat16(fast_gelu(acc[i][j][r] + bv));
          }
        }
      }
    }
    __syncthreads();
#pragma unroll
    for (int it = 0; it < 4; ++it) {
      const int m = it * 16 + rsub;
      const int pg = (lg >> 1) ^ (m & 7);
      const uint4 val = *(const uint4*)&SB[m * 128 + (pg << 4) + (lg & 1) * 8];
      *(uint4*)&C[(size_t)(rowBase + p * 64 + m) * ldc + colBase + lg * 8] = val;
    }
  }
}

__global__ __launch_bounds__(256, 2) void gemm_acc_kernel(
    const __hip_bfloat16* __restrict__ A, const __hip_bfloat16* __restrict__ Bt,
    const float* __restrict__ bias, const float* __restrict__ resid,
    float* __restrict__ X, int K, int ldb, int first) {
  __shared__ alignas(16) unsigned short SU[8192];
  unsigned short* As = SU;
  unsigned short* Bs = SU + 4096;
  const int tid = threadIdx.x;
  const int w = tid >> 6;
  const int lane = tid & 63;
  const int bid = blockIdx.x;
  const int NC = 4;
  const int rowT = (bid / (NC * 8)) * 8 + (bid & 7);
  const int colT = (bid >> 3) % NC;
  const int rowBase = rowT * 128;
  const int colBase = colT * 128;
  const int warpRow = w >> 1;
  const int warpCol = w & 1;
  const int q = lane >> 4;
  const int mr = lane & 15;
  const int srow = lane >> 2;
  const int skc = (((lane & 3) ^ ((srow >> 1) & 3))) * 8;
  const int jsA = q ^ ((mr >> 1) & 3);

  f32x4 acc[4][4] = {};

  for (int k0 = 0; k0 < K; k0 += 32) {
    __syncthreads();
#pragma unroll
    for (int i = 0; i < 2; ++i) {
      const int c = i * 4 + w;
      const int row = c * 16 + srow;
      async_ld16(&A[(size_t)(rowBase + row) * K + (k0 + skc)], (void*)&As[c * 512]);
      async_ld16(&Bt[(size_t)(colBase + row) * ldb + (k0 + skc)], (void*)&Bs[c * 512]);
    }
    __syncthreads();
    bf16x8 af[4], bf[4];
#pragma unroll
    for (int i = 0; i < 4; ++i)
      af[i] = *reinterpret_cast<const bf16x8*>(&As[(warpRow * 64 + i * 16 + mr) * 32 + jsA * 8]);
#pragma unroll
    for (int j = 0; j < 4; ++j)
      bf[j] = *reinterpret_cast<const bf16x8*>(&Bs[(warpCol * 64 + j * 16 + mr) * 32 + jsA * 8]);
#pragma unroll
    for (int i = 0; i < 4; ++i)
#pragma unroll
      for (int j = 0; j < 4; ++j)
        acc[i][j] = __builtin_amdgcn_mfma_f32_16x16x32_bf16(af[i], bf[j], acc[i][j], 0, 0, 0);
  }

#pragma unroll
  for (int j = 0; j < 4; ++j) {
    const int n = colBase + warpCol * 64 + j * 16 + mr;
    const float bv = bias[n];
#pragma unroll
    for (int i = 0; i < 4; ++i) {
#pragma unroll
      for (int r = 0; r < 4; ++r) {
        const int m = rowBase + warpRow * 64 + i * 16 + q * 4 + r;
        const size_t idx = (size_t)m * N_ + n;
        const float base = first ? (resid[idx] + bv) : X[idx];
        X[idx] = base + acc[i][j][r];
      }
    }
  }
}

// ---------------------------------------------------------------------------
// Fused per-(b,route) pool
// ---------------------------------------------------------------------------
__global__ __launch_bounds__(256) void route_pool_kernel(
    const float* __restrict__ X, const int* __restrict__ route_ids,
    const void* __restrict__ mask_raw, const int* __restrict__ flag,
    const float* __restrict__ gw, const float* __restrict__ gb,
    const float* __restrict__ ww, const float* __restrict__ wbias,
    float* __restrict__ routes, int* __restrict__ present) {
  const int b = blockIdx.x >> 5;
  const int r = blockIdx.x & 31;
  const int tid = threadIdx.x;
  __shared__ int cnt;
  __shared__ int ls[N_];
  __shared__ float lw[N_];
  if (tid == 0) cnt = 0;
  __syncthreads();
  const int fl = flag[0];
  for (int n = tid; n < N_; n += 256) {
    const int mk = fl ? (int)((const unsigned char*)mask_raw)[b * N_ + n]
                      : ((const int*)mask_raw)[b * N_ + n];
    if (route_ids[n] == r && mk != 0) {
      int p = atomicAdd(&cnt, 1);
      ls[p] = n;
    }
  }
  __syncthreads();
  const int c = cnt;
  const int wv = tid >> 6, lane = tid & 63;
  for (int t = wv; t < c; t += 4) {
    const float* p = X + ((size_t)b * N_ + ls[t]) * D_ + lane * 8;
    const float4 v0 = *(const float4*)p;
    const float4 v1 = *(const float4*)(p + 4);
    float s = v0.x + v0.y + v0.z + v0.w + v1.x + v1.y + v1.z + v1.w;
    float ss = v0.x * v0.x + v0.y * v0.y + v0.z * v0.z + v0.w * v0.w +
               v1.x * v1.x + v1.y * v1.y + v1.z * v1.z + v1.w * v1.w;
#pragma unroll
    for (int m = 32; m > 0; m >>= 1) {
      s += __shfl_xor(s, m);
      ss += __shfl_xor(ss, m);
    }
    const float mu = s * (1.0f / D_);
    const float rstd = rsqrtf(ss * (1.0f / D_) - mu * mu + 1e-5f);
    const float4 g0 = *(const float4*)(gw + lane * 8);
    const float4 g1 = *(const float4*)(gw + lane * 8 + 4);
    const float4 b0 = *(const float4*)(gb + lane * 8);
    const float4 b1v = *(const float4*)(gb + lane * 8 + 4);
    const float4 w0 = *(const float4*)(ww + lane * 8);
    const float4 w1v = *(const float4*)(ww + lane * 8 + 4);
    const float vv[8] = {v0.x, v0.y, v0.z, v0.w, v1.x, v1.y, v1.z, v1.w};
    const float gg[8] = {g0.x, g0.y, g0.z, g0.w, g1.x, g1.y, g1.z, g1.w};
    const float bb[8] = {b0.x, b0.y, b0.z, b0.w, b1v.x, b1v.y, b1v.z, b1v.w};
    const float wwv[8] = {w0.x, w0.y, w0.z, w0.w, w1v.x, w1v.y, w1v.z, w1v.w};
    float a = 0.f;
#pragma unroll
    for (int t2 = 0; t2 < 8; ++t2) a += ((vv[t2] - mu) * rstd * gg[t2] + bb[t2]) * wwv[t2];
#pragma unroll
    for (int m = 32; m > 0; m >>= 1) a += __shfl_xor(a, m);
    if (lane == 0) lw[t] = a + wbias[0];
  }
  __syncthreads();
  if (tid == 0 && c > 0) {
    float mx = -1e30f;
    for (int i = 0; i < c; ++i) mx = fmaxf(mx, lw[i]);
    float sm = 0.f;
    for (int i = 0; i < c; ++i) {
      const float e = __expf(lw[i] - mx);
      lw[i] = e;
      sm += e;
    }
    const float inv = 1.0f / sm;
    for (int i = 0; i < c; ++i) lw[i] *= inv;
  }
  __syncthreads();
  float a0 = 0.f, a1 = 0.f;
  for (int i = 0; i < c; ++i) {
    const float* xr = X + ((size_t)b * N_ + ls[i]) * D_;
    const float wgt = lw[i];
    a0 += wgt * xr[tid];
    a1 += wgt * xr[tid + 256];
  }
  float* outp = routes + ((size_t)b * R_ + r) * D_;
  outp[tid] = a0;
  outp[tid + 256] = a1;
  if (tid == 0) present[b * R_ + r] = (c > 0) ? 1 : 0;
}

// ---------------------------------------------------------------------------
// Final pool over routes
// ---------------------------------------------------------------------------
__global__ __launch_bounds__(512) void final_pool_kernel(
    const float* __restrict__ routes, const int* __restrict__ present,
    const float* __restrict__ gw, const float* __restrict__ gb,
    const float* __restrict__ ww, const float* __restrict__ wbias,
    float* __restrict__ out) {
  const int b = blockIdx.x;
  const int wv = threadIdx.x >> 6, lane = threadIdx.x & 63;
  __shared__ float srw[R_];
  __shared__ float srl[R_];
  for (int r = wv; r < R_; r += 8) {
    const float* p = routes + ((size_t)b * R_ + r) * D_ + lane * 8;
    const float4 v0 = *(const float4*)p;
    const float4 v1 = *(const float4*)(p + 4);
    float s = v0.x + v0.y + v0.z + v0.w + v1.x + v1.y + v1.z + v1.w;
    float ss = v0.x * v0.x + v0.y * v0.y + v0.z * v0.z + v0.w * v0.w +
               v1.x * v1.x + v1.y * v1.y + v1.z * v1.z + v1.w * v1.w;
#pragma unroll
    for (int m = 32; m > 0; m >>= 1) {
      s += __shfl_xor(s, m);
      ss += __shfl_xor(ss, m);
    }
    const float mu = s * (1.0f / D_);
    const float rstd = rsqrtf(ss * (1.0f / D_) - mu * mu + 1e-5f);
    const float4 g0 = *(const float4*)(gw + lane * 8);
    const float4 g1 = *(const float4*)(gw + lane * 8 + 4);
    const float4 b0 = *(const float4*)(gb + lane * 8);
    const float4 b1v = *(const float4*)(gb + lane * 8 + 4);
    const float4 w0 = *(const float4*)(ww + lane * 8);
    const float4 w1v = *(const float4*)(ww + lane * 8 + 4);
    const float vv[8] = {v0.x, v0.y, v0.z, v0.w, v1.x, v1.y, v1.z, v1.w};
    const float gg[8] = {g0.x, g0.y, g0.z, g0.w, g1.x, g1.y, g1.z, g1.w};
    const float bb[8] = {b0.x, b0.y, b0.z, b0.w, b1v.x, b1v.y, b1v.z, b1v.w};
    const float wwv[8] = {w0.x, w0.y, w0.z, w0.w, w1v.x, w1v.y, w1v.z, w1v.w};
    float a = 0.f;
#pragma unroll
    for (int t = 0; t < 8; ++t) a += ((vv[t] - mu) * rstd * gg[t] + bb[t]) * wwv[t];
#pragma unroll
    for (int m = 32; m > 0; m >>= 1) a += __shfl_xor(a, m);
    if (lane == 0) srl[r] = a + wbias[0];
  }
  __syncthreads();
  if (threadIdx.x == 0) {
    float mx = -1e30f;
    for (int r = 0; r < R_; ++r)
      if (present[b * R_ + r]) mx = fmaxf(mx, srl[r]);
    float sm = 0.f;
    for (int r = 0; r < R_; ++r) {
      const float e = present[b * R_ + r] ? __expf(srl[r] - mx) : 0.f;
      srw[r] = e;
      sm += e;
    }
    const float inv = (sm > 0.f) ? 1.0f / sm : 0.f;
    for (int r = 0; r < R_; ++r) srw[r] *= inv;
  }
  __syncthreads();
  const int d = threadIdx.x;
  float a = 0.f;
  for (int r = 0; r < R_; ++r) a += srw[r] * routes[((size_t)b * R_ + r) * D_ + d];
  out[(size_t)b * D_ + d] = a;
}

// ---------------------------------------------------------------------------
extern "C" void kernel_launch(void* const* d_in, const int* in_sizes, int n_in,
                              void* d_out, int out_size, void* d_ws, size_t ws_size,
                              hipStream_t stream) {
  const float* tokens = (const float*)d_in[0];
  const void* mask_raw = d_in[1];
  const int* route_ids = (const int*)d_in[2];
  const float* ln1_g = (const float*)d_in[3];
  const float* ln1_b = (const float*)d_in[4];
  const float* w1 = (const float*)d_in[5];
  const float* b1 = (const float*)d_in[6];
  const float* w2 = (const float*)d_in[7];
  const float* b2 = (const float*)d_in[8];
  const float* wp_g = (const float*)d_in[9];
  const float* wp_b = (const float*)d_in[10];
  const float* wp_w = (const float*)d_in[11];
  const float* wp_bias = (const float*)d_in[12];
  const float* rp_g = (const float*)d_in[13];
  const float* rp_b = (const float*)d_in[14];
  const float* rp_w = (const float*)d_in[15];
  const float* rp_bias = (const float*)d_in[16];
  float* out = (float*)d_out;

  char* ws = (char*)d_ws;
  size_t off = 0;
  auto carve = [&](size_t bytes) -> void* {
    void* p = ws + off;
    off = (off + bytes + 255) & ~(size_t)255;
    return p;
  };

  __hip_bfloat16* w1t = (__hip_bfloat16*)carve((size_t)H_ * D_ * 2);  // [H, D]
  __hip_bfloat16* w2t = (__hip_bfloat16*)carve((size_t)D_ * H_ * 2);  // [D, H]
  __hip_bfloat16* aBf = (__hip_bfloat16*)carve((size_t)M_ * D_ * 2);  // LN1 out
  float* X = (float*)carve((size_t)M_ * D_ * 4);                      // FFN out
  int* flag = (int*)carve(256);
  int* present = (int*)carve((size_t)B_ * R_ * 4);
  float* routes = (float*)carve((size_t)B_ * R_ * D_ * 4);

  // Capability gate for the big-LDS fused kernel (host-side, deterministic,
  // graph-capture-safe: none of these touch the stream).
  bool fused_ok = false;
  {
    int maxShmPerMP = 0;
    if (hipDeviceGetAttribute(&maxShmPerMP,
                              hipDeviceAttributeMaxSharedMemoryPerMultiprocessor,
                              0) == hipSuccess &&
        maxShmPerMP >= FUSED_LDS) {
      (void)hipFuncSetAttribute((const void*)ffn_fused_kernel,
                                hipFuncAttributeMaxDynamicSharedMemorySize,
                                FUSED_LDS);
      int nb = 0;
      if (hipOccupancyMaxActiveBlocksPerMultiprocessor(
              &nb, ffn_fused_kernel, 512, (size_t)FUSED_LDS) == hipSuccess &&
          nb >= 1)
        fused_ok = true;
    }
  }

  mask_detect_kernel<<<1, 256, 0, stream>>>((const unsigned char*)mask_raw, flag);
  transpose_cast_kernel<<<dim3(H_ / 64, D_ / 64), 256, 0, stream>>>(w1, w1t, D_, H_);
  transpose_cast_kernel<<<dim3(D_ / 64, H_ / 64), 256, 0, stream>>>(w2, w2t, H_, D_);
  ln_rows_kernel<<<M_ / 8, 512, 0, stream>>>(tokens, ln1_g, ln1_b, aBf);

  if (fused_ok) {
    ffn_fused_kernel<<<M_ / 128, 512, FUSED_LDS, stream>>>(
        aBf, w1t, w2t, b1, b2, tokens, X);
  } else {
    int G = 1;
    while (G < 16 && off + (size_t)M_ * (H_ / G) * 2 > ws_size) G <<= 1;
    const int Hg = H_ / G;
    __hip_bfloat16* hbuf = (__hip_bfloat16*)carve((size_t)M_ * Hg * 2);
    const int NC1 = Hg / 128;
    for (int g = 0; g < G; ++g) {
      gemm_bias_gelu_kernel<<<(M_ / 128) * NC1, 256, 0, stream>>>(
          aBf, w1t + (size_t)g * Hg * D_, b1 + (size_t)g * Hg, hbuf, D_, Hg, NC1);
      gemm_acc_kernel<<<(M_ / 128) * 4, 256, 0, stream>>>(
          hbuf, w2t + (size_t)g * Hg, b2, tokens, X, Hg, H_, (g == 0) ? 1 : 0);
    }
  }

  route_pool_kernel<<<B_ * R_, 256, 0, stream>>>(
      X, route_ids, mask_raw, flag, wp_g, wp_b, wp_w, wp_bias, routes, present);
  final_pool_kernel<<<B_, 512, 0, stream>>>(routes, present, rp_g, rp_b, rp_w, rp_bias, out);
}

// Round 4
// 368.179 us; speedup vs baseline: 1.3119x; 1.1464x over previous
//
#include <hip/hip_runtime.h>
#include <hip/hip_bf16.h>
#include <math.h>

// Problem constants (B=64, N=512, D=512, H=4D=2048, R=32 routes)
#define B_ 64
#define N_ 512
#define D_ 512
#define H_ 2048
#define R_ 32
#define M_ (B_ * N_)  // 32768 token rows

typedef __bf16 bf16x8 __attribute__((ext_vector_type(8)));
typedef float f32x4 __attribute__((ext_vector_type(4)));

__device__ __forceinline__ void async_ld16(const void* g, void* l) {
  __builtin_amdgcn_global_load_lds((__attribute__((address_space(1))) void*)g,
                                   (__attribute__((address_space(3))) void*)l,
                                   16, 0, 0);
}

// Abramowitz-Stegun 7.1.26 erf (max err 1.5e-7) with single-instr rcp.
__device__ __forceinline__ float fast_gelu(float v) {
  const float s = v * 0.70710678118654752f;
  const float a = fabsf(s);
  const float t = __builtin_amdgcn_rcpf(fmaf(0.3275911f, a, 1.0f));
  const float poly = t * fmaf(t, fmaf(t, fmaf(t, fmaf(t, 1.061405429f, -1.453152027f),
                                              1.421413741f), -0.284496736f), 0.254829592f);
  const float er = 1.0f - poly * __expf(-a * a);
  return 0.5f * v * (1.0f + ((s >= 0.f) ? er : -er));
}

// ---------------------------------------------------------------------------
// PREP (one launch): bid 0 = mask dtype detect; bid 1..512 = w1/w2 transpose
// +cast; bid 513..4608 = LayerNorm rows -> bf16. 512 threads.
// ---------------------------------------------------------------------------
__global__ __launch_bounds__(512) void prep_kernel(
    const float* __restrict__ tokens, const void* __restrict__ mask_raw,
    const float* __restrict__ ln1_g, const float* __restrict__ ln1_b,
    const float* __restrict__ w1, const float* __restrict__ w2,
    __hip_bfloat16* __restrict__ aBf, __hip_bfloat16* __restrict__ w1t,
    __hip_bfloat16* __restrict__ w2t, int* __restrict__ flag) {
  const int bid = blockIdx.x;
  const int tid = threadIdx.x;
  if (bid == 0) {
    __shared__ int f;
    if (tid == 0) f = 0;
    __syncthreads();
    const uint4* p = (const uint4*)mask_raw;
    unsigned acc = 0;
    for (int k = tid; k < M_ / 16; k += 512) {
      const uint4 v = p[k];
      acc |= (v.x | v.y | v.z | v.w) & 0xFFFFFF00u;
    }
    if (acc) f = 1;  // benign race
    __syncthreads();
    if (tid == 0) flag[0] = f;
  } else if (bid <= 512) {
    __shared__ float tile[64][65];
    const int t = bid - 1;
    const float* src;
    __hip_bfloat16* dst;
    int R, C, cx, ry;
    if (t < 256) { src = w1; dst = w1t; R = 512; C = 2048; cx = t & 31; ry = t >> 5; }
    else { const int t2 = t - 256; src = w2; dst = w2t; R = 2048; C = 512; cx = t2 & 7; ry = t2 >> 3; }
    const int c0 = cx * 64, r0 = ry * 64;
    const int tx = tid & 63, ty = tid >> 6;
    for (int r = ty; r < 64; r += 8)
      tile[r][tx] = src[(size_t)(r0 + r) * C + c0 + tx];
    __syncthreads();
    for (int r = ty; r < 64; r += 8)
      dst[(size_t)(c0 + r) * R + r0 + tx] = __float2bfloat16(tile[tx][r]);
  } else {
    const int wv = tid >> 6, lane = tid & 63;
    const int row = (bid - 513) * 8 + wv;
    const float* p = tokens + (size_t)row * D_ + lane * 8;
    const float4 v0 = *(const float4*)p;
    const float4 v1 = *(const float4*)(p + 4);
    float s = v0.x + v0.y + v0.z + v0.w + v1.x + v1.y + v1.z + v1.w;
    float ss = v0.x * v0.x + v0.y * v0.y + v0.z * v0.z + v0.w * v0.w +
               v1.x * v1.x + v1.y * v1.y + v1.z * v1.z + v1.w * v1.w;
#pragma unroll
    for (int m = 32; m > 0; m >>= 1) {
      s += __shfl_xor(s, m);
      ss += __shfl_xor(ss, m);
    }
    const float mu = s * (1.0f / D_);
    const float rstd = rsqrtf(ss * (1.0f / D_) - mu * mu + 1e-5f);
    const float4 g0 = *(const float4*)(ln1_g + lane * 8);
    const float4 g1 = *(const float4*)(ln1_g + lane * 8 + 4);
    const float4 b0 = *(const float4*)(ln1_b + lane * 8);
    const float4 b1 = *(const float4*)(ln1_b + lane * 8 + 4);
    const float vv[8] = {v0.x, v0.y, v0.z, v0.w, v1.x, v1.y, v1.z, v1.w};
    const float gg[8] = {g0.x, g0.y, g0.z, g0.w, g1.x, g1.y, g1.z, g1.w};
    const float bb[8] = {b0.x, b0.y, b0.z, b0.w, b1.x, b1.y, b1.z, b1.w};
    union { __hip_bfloat16 h[8]; uint4 u; } pk;
#pragma unroll
    for (int t2 = 0; t2 < 8; ++t2)
      pk.h[t2] = __float2bfloat16((vv[t2] - mu) * rstd * gg[t2] + bb[t2]);
    *(uint4*)(aBf + (size_t)row * D_ + lane * 8) = pk.u;
  }
}

// ---------------------------------------------------------------------------
// GEMM1: C = gelu(A @ Bt^T + bias). 128x128 tile, BK=32, 16x16x32 MFMA.
// K-loop: global-side k-chunk XOR swizzle (conflict-free ds_read_b128) +
// supertile grid swizzle. Epilogue: single-pass 32 KB LDS restage (all waves
// active), XOR-slot layout, coalesced 16B/lane bf16 stores.
// ---------------------------------------------------------------------------
__global__ __launch_bounds__(256, 2) void gemm_bias_gelu_kernel(
    const __hip_bfloat16* __restrict__ A, const __hip_bfloat16* __restrict__ Bt,
    const float* __restrict__ bias, __hip_bfloat16* __restrict__ C,
    int K, int ldc, int NC) {
  __shared__ alignas(16) unsigned short SU[16384];  // 32 KB
  unsigned short* As = SU;
  unsigned short* Bs = SU + 4096;
  const int tid = threadIdx.x;
  const int w = tid >> 6;
  const int lane = tid & 63;
  const int bid = blockIdx.x;
  const int rowT = (bid / (NC * 8)) * 8 + (bid & 7);
  const int colT = (bid >> 3) % NC;
  const int rowBase = rowT * 128;
  const int colBase = colT * 128;
  const int warpRow = w >> 1;
  const int warpCol = w & 1;
  const int q = lane >> 4;
  const int mr = lane & 15;
  const int srow = lane >> 2;
  const int skc = (((lane & 3) ^ ((srow >> 1) & 3))) * 8;  // swizzled k-chunk
  const int jsA = q ^ ((mr >> 1) & 3);                     // fragment k-slot

  f32x4 acc[4][4] = {};

  for (int k0 = 0; k0 < K; k0 += 32) {
    __syncthreads();
#pragma unroll
    for (int i = 0; i < 2; ++i) {
      const int c = i * 4 + w;
      const int row = c * 16 + srow;
      async_ld16(&A[(size_t)(rowBase + row) * K + (k0 + skc)], (void*)&As[c * 512]);
      async_ld16(&Bt[(size_t)(colBase + row) * K + (k0 + skc)], (void*)&Bs[c * 512]);
    }
    __syncthreads();
    bf16x8 af[4], bf[4];
#pragma unroll
    for (int i = 0; i < 4; ++i)
      af[i] = *reinterpret_cast<const bf16x8*>(&As[(warpRow * 64 + i * 16 + mr) * 32 + jsA * 8]);
#pragma unroll
    for (int j = 0; j < 4; ++j)
      bf[j] = *reinterpret_cast<const bf16x8*>(&Bs[(warpCol * 64 + j * 16 + mr) * 32 + jsA * 8]);
#pragma unroll
    for (int i = 0; i < 4; ++i)
#pragma unroll
      for (int j = 0; j < 4; ++j)
        acc[i][j] = __builtin_amdgcn_mfma_f32_16x16x32_bf16(af[i], bf[j], acc[i][j], 0, 0, 0);
  }

  // ---- single-pass epilogue: full 128x128 bf16 tile in 32 KB LDS ----
  __syncthreads();  // last iter's fragment reads complete
  __hip_bfloat16* SB = (__hip_bfloat16*)SU;
#pragma unroll
  for (int j = 0; j < 4; ++j) {
    const int col = warpCol * 64 + j * 16 + mr;
    const float bv = bias[colBase + col];
#pragma unroll
    for (int i = 0; i < 4; ++i) {
#pragma unroll
      for (int r = 0; r < 4; ++r) {
        const int row = warpRow * 64 + i * 16 + q * 4 + r;
        const int slot = (col >> 3) ^ (row & 7);  // 4-bit slot, low-3 XOR
        SB[row * 128 + slot * 8 + (col & 7)] =
            __float2bfloat16(fast_gelu(acc[i][j][r] + bv));
      }
    }
  }
  __syncthreads();
  const int lg = tid & 15, rsub = tid >> 4;
#pragma unroll
  for (int it = 0; it < 8; ++it) {
    const int m = it * 16 + rsub;
    const int slot = lg ^ (m & 7);
    const uint4 val = *(const uint4*)&SB[m * 128 + slot * 8];
    *(uint4*)&C[(size_t)(rowBase + m) * ldc + colBase + lg * 8] = val;
  }
}

// ---------------------------------------------------------------------------
// GEMM2: X = resid + bias + A @ Bt^T  (fp32 out w/ residual; dword stores
// already fill full lines — no restage needed)
// ---------------------------------------------------------------------------
__global__ __launch_bounds__(256, 2) void gemm_acc_kernel(
    const __hip_bfloat16* __restrict__ A, const __hip_bfloat16* __restrict__ Bt,
    const float* __restrict__ bias, const float* __restrict__ resid,
    float* __restrict__ X, int K, int ldb, int first) {
  __shared__ alignas(16) unsigned short SU[8192];
  unsigned short* As = SU;
  unsigned short* Bs = SU + 4096;
  const int tid = threadIdx.x;
  const int w = tid >> 6;
  const int lane = tid & 63;
  const int bid = blockIdx.x;
  const int NC = 4;
  const int rowT = (bid / (NC * 8)) * 8 + (bid & 7);
  const int colT = (bid >> 3) % NC;
  const int rowBase = rowT * 128;
  const int colBase = colT * 128;
  const int warpRow = w >> 1;
  const int warpCol = w & 1;
  const int q = lane >> 4;
  const int mr = lane & 15;
  const int srow = lane >> 2;
  const int skc = (((lane & 3) ^ ((srow >> 1) & 3))) * 8;
  const int jsA = q ^ ((mr >> 1) & 3);

  f32x4 acc[4][4] = {};

  for (int k0 = 0; k0 < K; k0 += 32) {
    __syncthreads();
#pragma unroll
    for (int i = 0; i < 2; ++i) {
      const int c = i * 4 + w;
      const int row = c * 16 + srow;
      async_ld16(&A[(size_t)(rowBase + row) * K + (k0 + skc)], (void*)&As[c * 512]);
      async_ld16(&Bt[(size_t)(colBase + row) * ldb + (k0 + skc)], (void*)&Bs[c * 512]);
    }
    __syncthreads();
    bf16x8 af[4], bf[4];
#pragma unroll
    for (int i = 0; i < 4; ++i)
      af[i] = *reinterpret_cast<const bf16x8*>(&As[(warpRow * 64 + i * 16 + mr) * 32 + jsA * 8]);
#pragma unroll
    for (int j = 0; j < 4; ++j)
      bf[j] = *reinterpret_cast<const bf16x8*>(&Bs[(warpCol * 64 + j * 16 + mr) * 32 + jsA * 8]);
#pragma unroll
    for (int i = 0; i < 4; ++i)
#pragma unroll
      for (int j = 0; j < 4; ++j)
        acc[i][j] = __builtin_amdgcn_mfma_f32_16x16x32_bf16(af[i], bf[j], acc[i][j], 0, 0, 0);
  }

#pragma unroll
  for (int j = 0; j < 4; ++j) {
    const int n = colBase + warpCol * 64 + j * 16 + mr;
    const float bv = bias[n];
#pragma unroll
    for (int i = 0; i < 4; ++i) {
#pragma unroll
      for (int r = 0; r < 4; ++r) {
        const int m = rowBase + warpRow * 64 + i * 16 + q * 4 + r;
        const size_t idx = (size_t)m * N_ + n;
        const float base = first ? (resid[idx] + bv) : X[idx];
        X[idx] = base + acc[i][j][r];
      }
    }
  }
}

// ---------------------------------------------------------------------------
// Fused per-(b,route) pool: select tokens, LN+dot logits, masked softmax,
// weighted sum -> routes
// ---------------------------------------------------------------------------
__global__ __launch_bounds__(256) void route_pool_kernel(
    const float* __restrict__ X, const int* __restrict__ route_ids,
    const void* __restrict__ mask_raw, const int* __restrict__ flag,
    const float* __restrict__ gw, const float* __restrict__ gb,
    const float* __restrict__ ww, const float* __restrict__ wbias,
    float* __restrict__ routes, int* __restrict__ present) {
  const int b = blockIdx.x >> 5;
  const int r = blockIdx.x & 31;
  const int tid = threadIdx.x;
  __shared__ int cnt;
  __shared__ int ls[N_];
  __shared__ float lw[N_];
  if (tid == 0) cnt = 0;
  __syncthreads();
  const int fl = flag[0];
  for (int n = tid; n < N_; n += 256) {
    const int mk = fl ? (int)((const unsigned char*)mask_raw)[b * N_ + n]
                      : ((const int*)mask_raw)[b * N_ + n];
    if (route_ids[n] == r && mk != 0) {
      int p = atomicAdd(&cnt, 1);
      ls[p] = n;
    }
  }
  __syncthreads();
  const int c = cnt;
  const int wv = tid >> 6, lane = tid & 63;
  for (int t = wv; t < c; t += 4) {
    const float* p = X + ((size_t)b * N_ + ls[t]) * D_ + lane * 8;
    const float4 v0 = *(const float4*)p;
    const float4 v1 = *(const float4*)(p + 4);
    float s = v0.x + v0.y + v0.z + v0.w + v1.x + v1.y + v1.z + v1.w;
    float ss = v0.x * v0.x + v0.y * v0.y + v0.z * v0.z + v0.w * v0.w +
               v1.x * v1.x + v1.y * v1.y + v1.z * v1.z + v1.w * v1.w;
#pragma unroll
    for (int m = 32; m > 0; m >>= 1) {
      s += __shfl_xor(s, m);
      ss += __shfl_xor(ss, m);
    }
    const float mu = s * (1.0f / D_);
    const float rstd = rsqrtf(ss * (1.0f / D_) - mu * mu + 1e-5f);
    const float4 g0 = *(const float4*)(gw + lane * 8);
    const float4 g1 = *(const float4*)(gw + lane * 8 + 4);
    const float4 b0 = *(const float4*)(gb + lane * 8);
    const float4 b1v = *(const float4*)(gb + lane * 8 + 4);
    const float4 w0 = *(const float4*)(ww + lane * 8);
    const float4 w1v = *(const float4*)(ww + lane * 8 + 4);
    const float vv[8] = {v0.x, v0.y, v0.z, v0.w, v1.x, v1.y, v1.z, v1.w};
    const float gg[8] = {g0.x, g0.y, g0.z, g0.w, g1.x, g1.y, g1.z, g1.w};
    const float bb[8] = {b0.x, b0.y, b0.z, b0.w, b1v.x, b1v.y, b1v.z, b1v.w};
    const float wwv[8] = {w0.x, w0.y, w0.z, w0.w, w1v.x, w1v.y, w1v.z, w1v.w};
    float a = 0.f;
#pragma unroll
    for (int t2 = 0; t2 < 8; ++t2) a += ((vv[t2] - mu) * rstd * gg[t2] + bb[t2]) * wwv[t2];
#pragma unroll
    for (int m = 32; m > 0; m >>= 1) a += __shfl_xor(a, m);
    if (lane == 0) lw[t] = a + wbias[0];
  }
  __syncthreads();
  if (tid == 0 && c > 0) {
    float mx = -1e30f;
    for (int i = 0; i < c; ++i) mx = fmaxf(mx, lw[i]);
    float sm = 0.f;
    for (int i = 0; i < c; ++i) {
      const float e = __expf(lw[i] - mx);
      lw[i] = e;
      sm += e;
    }
    const float inv = 1.0f / sm;
    for (int i = 0; i < c; ++i) lw[i] *= inv;
  }
  __syncthreads();
  float a0 = 0.f, a1 = 0.f;
  for (int i = 0; i < c; ++i) {
    const float* xr = X + ((size_t)b * N_ + ls[i]) * D_;
    const float wgt = lw[i];
    a0 += wgt * xr[tid];
    a1 += wgt * xr[tid + 256];
  }
  float* outp = routes + ((size_t)b * R_ + r) * D_;
  outp[tid] = a0;
  outp[tid + 256] = a1;
  if (tid == 0) present[b * R_ + r] = (c > 0) ? 1 : 0;
}

// ---------------------------------------------------------------------------
// Final pool over routes (one block of 512 per batch)
// ---------------------------------------------------------------------------
__global__ __launch_bounds__(512) void final_pool_kernel(
    const float* __restrict__ routes, const int* __restrict__ present,
    const float* __restrict__ gw, const float* __restrict__ gb,
    const float* __restrict__ ww, const float* __restrict__ wbias,
    float* __restrict__ out) {
  const int b = blockIdx.x;
  const int wv = threadIdx.x >> 6, lane = threadIdx.x & 63;
  __shared__ float srw[R_];
  __shared__ float srl[R_];
  for (int r = wv; r < R_; r += 8) {
    const float* p = routes + ((size_t)b * R_ + r) * D_ + lane * 8;
    const float4 v0 = *(const float4*)p;
    const float4 v1 = *(const float4*)(p + 4);
    float s = v0.x + v0.y + v0.z + v0.w + v1.x + v1.y + v1.z + v1.w;
    float ss = v0.x * v0.x + v0.y * v0.y + v0.z * v0.z + v0.w * v0.w +
               v1.x * v1.x + v1.y * v1.y + v1.z * v1.z + v1.w * v1.w;
#pragma unroll
    for (int m = 32; m > 0; m >>= 1) {
      s += __shfl_xor(s, m);
      ss += __shfl_xor(ss, m);
    }
    const float mu = s * (1.0f / D_);
    const float rstd = rsqrtf(ss * (1.0f / D_) - mu * mu + 1e-5f);
    const float4 g0 = *(const float4*)(gw + lane * 8);
    const float4 g1 = *(const float4*)(gw + lane * 8 + 4);
    const float4 b0 = *(const float4*)(gb + lane * 8);
    const float4 b1v = *(const float4*)(gb + lane * 8 + 4);
    const float4 w0 = *(const float4*)(ww + lane * 8);
    const float4 w1v = *(const float4*)(ww + lane * 8 + 4);
    const float vv[8] = {v0.x, v0.y, v0.z, v0.w, v1.x, v1.y, v1.z, v1.w};
    const float gg[8] = {g0.x, g0.y, g0.z, g0.w, g1.x, g1.y, g1.z, g1.w};
    const float bb[8] = {b0.x, b0.y, b0.z, b0.w, b1v.x, b1v.y, b1v.z, b1v.w};
    const float wwv[8] = {w0.x, w0.y, w0.z, w0.w, w1v.x, w1v.y, w1v.z, w1v.w};
    float a = 0.f;
#pragma unroll
    for (int t = 0; t < 8; ++t) a += ((vv[t] - mu) * rstd * gg[t] + bb[t]) * wwv[t];
#pragma unroll
    for (int m = 32; m > 0; m >>= 1) a += __shfl_xor(a, m);
    if (lane == 0) srl[r] = a + wbias[0];
  }
  __syncthreads();
  if (threadIdx.x == 0) {
    float mx = -1e30f;
    for (int r = 0; r < R_; ++r)
      if (present[b * R_ + r]) mx = fmaxf(mx, srl[r]);
    float sm = 0.f;
    for (int r = 0; r < R_; ++r) {
      const float e = present[b * R_ + r] ? __expf(srl[r] - mx) : 0.f;
      srw[r] = e;
      sm += e;
    }
    const float inv = (sm > 0.f) ? 1.0f / sm : 0.f;
    for (int r = 0; r < R_; ++r) srw[r] *= inv;
  }
  __syncthreads();
  const int d = threadIdx.x;
  float a = 0.f;
  for (int r = 0; r < R_; ++r) a += srw[r] * routes[((size_t)b * R_ + r) * D_ + d];
  out[(size_t)b * D_ + d] = a;
}

// ---------------------------------------------------------------------------
extern "C" void kernel_launch(void* const* d_in, const int* in_sizes, int n_in,
                              void* d_out, int out_size, void* d_ws, size_t ws_size,
                              hipStream_t stream) {
  const float* tokens = (const float*)d_in[0];
  const void* mask_raw = d_in[1];
  const int* route_ids = (const int*)d_in[2];
  const float* ln1_g = (const float*)d_in[3];
  const float* ln1_b = (const float*)d_in[4];
  const float* w1 = (const float*)d_in[5];
  const float* b1 = (const float*)d_in[6];
  const float* w2 = (const float*)d_in[7];
  const float* b2 = (const float*)d_in[8];
  const float* wp_g = (const float*)d_in[9];
  const float* wp_b = (const float*)d_in[10];
  const float* wp_w = (const float*)d_in[11];
  const float* wp_bias = (const float*)d_in[12];
  const float* rp_g = (const float*)d_in[13];
  const float* rp_b = (const float*)d_in[14];
  const float* rp_w = (const float*)d_in[15];
  const float* rp_bias = (const float*)d_in[16];
  float* out = (float*)d_out;

  char* ws = (char*)d_ws;
  size_t off = 0;
  auto carve = [&](size_t bytes) -> void* {
    void* p = ws + off;
    off = (off + bytes + 255) & ~(size_t)255;
    return p;
  };

  __hip_bfloat16* w1t = (__hip_bfloat16*)carve((size_t)H_ * D_ * 2);  // [H, D]
  __hip_bfloat16* w2t = (__hip_bfloat16*)carve((size_t)D_ * H_ * 2);  // [D, H]
  __hip_bfloat16* aBf = (__hip_bfloat16*)carve((size_t)M_ * D_ * 2);  // LN1 out
  float* X = (float*)carve((size_t)M_ * D_ * 4);                      // FFN out
  int* flag = (int*)carve(256);
  int* present = (int*)carve((size_t)B_ * R_ * 4);
  float* routes = (float*)carve((size_t)B_ * R_ * D_ * 4);

  int G = 1;
  while (G < 16 && off + (size_t)M_ * (H_ / G) * 2 > ws_size) G <<= 1;
  const int Hg = H_ / G;
  __hip_bfloat16* hbuf = (__hip_bfloat16*)carve((size_t)M_ * Hg * 2);

  // one launch: mask detect + w1/w2 transpose-cast + LN
  prep_kernel<<<513 + M_ / 8, 512, 0, stream>>>(
      tokens, mask_raw, ln1_g, ln1_b, w1, w2, aBf, w1t, w2t, flag);

  const int NC1 = Hg / 128;
  for (int g = 0; g < G; ++g) {
    gemm_bias_gelu_kernel<<<(M_ / 128) * NC1, 256, 0, stream>>>(
        aBf, w1t + (size_t)g * Hg * D_, b1 + (size_t)g * Hg, hbuf, D_, Hg, NC1);
    gemm_acc_kernel<<<(M_ / 128) * 4, 256, 0, stream>>>(
        hbuf, w2t + (size_t)g * Hg, b2, tokens, X, Hg, H_, (g == 0) ? 1 : 0);
  }

  route_pool_kernel<<<B_ * R_, 256, 0, stream>>>(
      X, route_ids, mask_raw, flag, wp_g, wp_b, wp_w, wp_bias, routes, present);
  final_pool_kernel<<<B_, 512, 0, stream>>>(routes, present, rp_g, rp_b, rp_w, rp_bias, out);
}

// Round 5
// 348.934 us; speedup vs baseline: 1.3842x; 1.0552x over previous
//
#include <hip/hip_runtime.h>
#include <hip/hip_bf16.h>
#include <math.h>

// Problem constants (B=64, N=512, D=512, H=4D=2048, R=32 routes)
#define B_ 64
#define N_ 512
#define D_ 512
#define H_ 2048
#define R_ 32
#define M_ (B_ * N_)  // 32768 token rows

typedef __bf16 bf16x8 __attribute__((ext_vector_type(8)));
typedef float f32x4 __attribute__((ext_vector_type(4)));

__device__ __forceinline__ void async_ld16(const void* g, void* l) {
  __builtin_amdgcn_global_load_lds((__attribute__((address_space(1))) void*)g,
                                   (__attribute__((address_space(3))) void*)l,
                                   16, 0, 0);
}

// Abramowitz-Stegun 7.1.26 erf (max err 1.5e-7) with single-instr rcp.
__device__ __forceinline__ float fast_gelu(float v) {
  const float s = v * 0.70710678118654752f;
  const float a = fabsf(s);
  const float t = __builtin_amdgcn_rcpf(fmaf(0.3275911f, a, 1.0f));
  const float poly = t * fmaf(t, fmaf(t, fmaf(t, fmaf(t, 1.061405429f, -1.453152027f),
                                              1.421413741f), -0.284496736f), 0.254829592f);
  const float er = 1.0f - poly * __expf(-a * a);
  return 0.5f * v * (1.0f + ((s >= 0.f) ? er : -er));
}

// ---------------------------------------------------------------------------
// PREP (one launch): bid 0 = mask dtype detect; bid 1..512 = w1/w2 transpose
// +cast; bid 513..4608 = LayerNorm rows -> bf16. 512 threads.
// ---------------------------------------------------------------------------
__global__ __launch_bounds__(512) void prep_kernel(
    const float* __restrict__ tokens, const void* __restrict__ mask_raw,
    const float* __restrict__ ln1_g, const float* __restrict__ ln1_b,
    const float* __restrict__ w1, const float* __restrict__ w2,
    __hip_bfloat16* __restrict__ aBf, __hip_bfloat16* __restrict__ w1t,
    __hip_bfloat16* __restrict__ w2t, int* __restrict__ flag) {
  const int bid = blockIdx.x;
  const int tid = threadIdx.x;
  if (bid == 0) {
    __shared__ int f;
    if (tid == 0) f = 0;
    __syncthreads();
    const uint4* p = (const uint4*)mask_raw;
    unsigned acc = 0;
    for (int k = tid; k < M_ / 16; k += 512) {
      const uint4 v = p[k];
      acc |= (v.x | v.y | v.z | v.w) & 0xFFFFFF00u;
    }
    if (acc) f = 1;  // benign race
    __syncthreads();
    if (tid == 0) flag[0] = f;
  } else if (bid <= 512) {
    __shared__ float tile[64][65];
    const int t = bid - 1;
    const float* src;
    __hip_bfloat16* dst;
    int R, C, cx, ry;
    if (t < 256) { src = w1; dst = w1t; R = 512; C = 2048; cx = t & 31; ry = t >> 5; }
    else { const int t2 = t - 256; src = w2; dst = w2t; R = 2048; C = 512; cx = t2 & 7; ry = t2 >> 3; }
    const int c0 = cx * 64, r0 = ry * 64;
    const int tx = tid & 63, ty = tid >> 6;
    for (int r = ty; r < 64; r += 8)
      tile[r][tx] = src[(size_t)(r0 + r) * C + c0 + tx];
    __syncthreads();
    for (int r = ty; r < 64; r += 8)
      dst[(size_t)(c0 + r) * R + r0 + tx] = __float2bfloat16(tile[tx][r]);
  } else {
    const int wv = tid >> 6, lane = tid & 63;
    const int row = (bid - 513) * 8 + wv;
    const float* p = tokens + (size_t)row * D_ + lane * 8;
    const float4 v0 = *(const float4*)p;
    const float4 v1 = *(const float4*)(p + 4);
    float s = v0.x + v0.y + v0.z + v0.w + v1.x + v1.y + v1.z + v1.w;
    float ss = v0.x * v0.x + v0.y * v0.y + v0.z * v0.z + v0.w * v0.w +
               v1.x * v1.x + v1.y * v1.y + v1.z * v1.z + v1.w * v1.w;
#pragma unroll
    for (int m = 32; m > 0; m >>= 1) {
      s += __shfl_xor(s, m);
      ss += __shfl_xor(ss, m);
    }
    const float mu = s * (1.0f / D_);
    const float rstd = rsqrtf(ss * (1.0f / D_) - mu * mu + 1e-5f);
    const float4 g0 = *(const float4*)(ln1_g + lane * 8);
    const float4 g1 = *(const float4*)(ln1_g + lane * 8 + 4);
    const float4 b0 = *(const float4*)(ln1_b + lane * 8);
    const float4 b1 = *(const float4*)(ln1_b + lane * 8 + 4);
    const float vv[8] = {v0.x, v0.y, v0.z, v0.w, v1.x, v1.y, v1.z, v1.w};
    const float gg[8] = {g0.x, g0.y, g0.z, g0.w, g1.x, g1.y, g1.z, g1.w};
    const float bb[8] = {b0.x, b0.y, b0.z, b0.w, b1.x, b1.y, b1.z, b1.w};
    union { __hip_bfloat16 h[8]; uint4 u; } pk;
#pragma unroll
    for (int t2 = 0; t2 < 8; ++t2)
      pk.h[t2] = __float2bfloat16((vv[t2] - mu) * rstd * gg[t2] + bb[t2]);
    *(uint4*)(aBf + (size_t)row * D_ + lane * 8) = pk.u;
  }
}

// ---------------------------------------------------------------------------
// GEMM1: C = gelu(A @ Bt^T + bias). 128x128 tile, BK=64 (32 MFMA/barrier),
// 16x16x32 MFMA. Staging: 8-slot k-chunk XOR swizzle applied on the global
// side (slot = chunk ^ (row&7)) -> conflict-free ds_read_b128 fragments.
// Epilogue: single-pass 32 KB LDS restage, coalesced 16B/lane bf16 stores.
// ---------------------------------------------------------------------------
__global__ __launch_bounds__(256, 2) void gemm_bias_gelu_kernel(
    const __hip_bfloat16* __restrict__ A, const __hip_bfloat16* __restrict__ Bt,
    const float* __restrict__ bias, __hip_bfloat16* __restrict__ C,
    int K, int ldc, int NC) {
  __shared__ alignas(16) unsigned short SU[16384];  // 32 KB: As | Bs (128x64 each)
  unsigned short* As = SU;
  unsigned short* Bs = SU + 8192;
  const int tid = threadIdx.x;
  const int w = tid >> 6;
  const int lane = tid & 63;
  const int bid = blockIdx.x;
  const int rowT = (bid / (NC * 8)) * 8 + (bid & 7);
  const int colT = (bid >> 3) % NC;
  const int rowBase = rowT * 128;
  const int colBase = colT * 128;
  const int warpRow = w >> 1;
  const int warpCol = w & 1;
  const int q = lane >> 4;
  const int mr = lane & 15;
  const int srow8 = lane >> 3;                  // 0..7 row within 8-row slab
  const int sg8 = ((lane & 7) ^ srow8) * 8;     // swizzled global k-offset (elems)
  const int mx7 = (mr & 7) * 8;                 // fragment slot XOR base (elems)

  f32x4 acc[4][4] = {};

  for (int k0 = 0; k0 < K; k0 += 64) {
    __syncthreads();
    {
      const __hip_bfloat16* Ak = A + (size_t)(rowBase + w * 32 + srow8) * K + k0 + sg8;
      const __hip_bfloat16* Bk = Bt + (size_t)(colBase + w * 32 + srow8) * K + k0 + sg8;
#pragma unroll
      for (int i = 0; i < 4; ++i) {
        async_ld16(Ak + (size_t)(i * 8) * K, (void*)&As[(w * 32 + i * 8) * 64]);
        async_ld16(Bk + (size_t)(i * 8) * K, (void*)&Bs[(w * 32 + i * 8) * 64]);
      }
    }
    __syncthreads();
#pragma unroll
    for (int s = 0; s < 2; ++s) {
      bf16x8 af[4], bf[4];
#pragma unroll
      for (int i = 0; i < 4; ++i)
        af[i] = *reinterpret_cast<const bf16x8*>(
            &As[(warpRow * 64 + i * 16 + mr) * 64 + (((s * 4 + q) * 8) ^ mx7)]);
#pragma unroll
      for (int j = 0; j < 4; ++j)
        bf[j] = *reinterpret_cast<const bf16x8*>(
            &Bs[(warpCol * 64 + j * 16 + mr) * 64 + (((s * 4 + q) * 8) ^ mx7)]);
#pragma unroll
      for (int i = 0; i < 4; ++i)
#pragma unroll
        for (int j = 0; j < 4; ++j)
          acc[i][j] = __builtin_amdgcn_mfma_f32_16x16x32_bf16(af[i], bf[j], acc[i][j], 0, 0, 0);
    }
  }

  // ---- single-pass epilogue: full 128x128 bf16 tile in 32 KB LDS ----
  __syncthreads();  // last iter's fragment reads complete
  __hip_bfloat16* SB = (__hip_bfloat16*)SU;
#pragma unroll
  for (int j = 0; j < 4; ++j) {
    const int col = warpCol * 64 + j * 16 + mr;
    const float bv = bias[colBase + col];
#pragma unroll
    for (int i = 0; i < 4; ++i) {
#pragma unroll
      for (int r = 0; r < 4; ++r) {
        const int row = warpRow * 64 + i * 16 + q * 4 + r;
        const int slot = (col >> 3) ^ (row & 7);  // 4-bit slot, low-3 XOR
        SB[row * 128 + slot * 8 + (col & 7)] =
            __float2bfloat16(fast_gelu(acc[i][j][r] + bv));
      }
    }
  }
  __syncthreads();
  const int lg = tid & 15, rsub = tid >> 4;
#pragma unroll
  for (int it = 0; it < 8; ++it) {
    const int m = it * 16 + rsub;
    const int slot = lg ^ (m & 7);
    const uint4 val = *(const uint4*)&SB[m * 128 + slot * 8];
    *(uint4*)&C[(size_t)(rowBase + m) * ldc + colBase + lg * 8] = val;
  }
}

// ---------------------------------------------------------------------------
// GEMM2: X = resid + bias + A @ Bt^T  (fp32 out w/ residual). BK=64.
// ---------------------------------------------------------------------------
__global__ __launch_bounds__(256, 2) void gemm_acc_kernel(
    const __hip_bfloat16* __restrict__ A, const __hip_bfloat16* __restrict__ Bt,
    const float* __restrict__ bias, const float* __restrict__ resid,
    float* __restrict__ X, int K, int ldb, int first) {
  __shared__ alignas(16) unsigned short SU[16384];
  unsigned short* As = SU;
  unsigned short* Bs = SU + 8192;
  const int tid = threadIdx.x;
  const int w = tid >> 6;
  const int lane = tid & 63;
  const int bid = blockIdx.x;
  const int NC = 4;
  const int rowT = (bid / (NC * 8)) * 8 + (bid & 7);
  const int colT = (bid >> 3) % NC;
  const int rowBase = rowT * 128;
  const int colBase = colT * 128;
  const int warpRow = w >> 1;
  const int warpCol = w & 1;
  const int q = lane >> 4;
  const int mr = lane & 15;
  const int srow8 = lane >> 3;
  const int sg8 = ((lane & 7) ^ srow8) * 8;
  const int mx7 = (mr & 7) * 8;

  f32x4 acc[4][4] = {};

  for (int k0 = 0; k0 < K; k0 += 64) {
    __syncthreads();
    {
      const __hip_bfloat16* Ak = A + (size_t)(rowBase + w * 32 + srow8) * K + k0 + sg8;
      const __hip_bfloat16* Bk = Bt + (size_t)(colBase + w * 32 + srow8) * ldb + k0 + sg8;
#pragma unroll
      for (int i = 0; i < 4; ++i) {
        async_ld16(Ak + (size_t)(i * 8) * K, (void*)&As[(w * 32 + i * 8) * 64]);
        async_ld16(Bk + (size_t)(i * 8) * ldb, (void*)&Bs[(w * 32 + i * 8) * 64]);
      }
    }
    __syncthreads();
#pragma unroll
    for (int s = 0; s < 2; ++s) {
      bf16x8 af[4], bf[4];
#pragma unroll
      for (int i = 0; i < 4; ++i)
        af[i] = *reinterpret_cast<const bf16x8*>(
            &As[(warpRow * 64 + i * 16 + mr) * 64 + (((s * 4 + q) * 8) ^ mx7)]);
#pragma unroll
      for (int j = 0; j < 4; ++j)
        bf[j] = *reinterpret_cast<const bf16x8*>(
            &Bs[(warpCol * 64 + j * 16 + mr) * 64 + (((s * 4 + q) * 8) ^ mx7)]);
#pragma unroll
      for (int i = 0; i < 4; ++i)
#pragma unroll
        for (int j = 0; j < 4; ++j)
          acc[i][j] = __builtin_amdgcn_mfma_f32_16x16x32_bf16(af[i], bf[j], acc[i][j], 0, 0, 0);
    }
  }

#pragma unroll
  for (int j = 0; j < 4; ++j) {
    const int n = colBase + warpCol * 64 + j * 16 + mr;
    const float bv = bias[n];
#pragma unroll
    for (int i = 0; i < 4; ++i) {
#pragma unroll
      for (int r = 0; r < 4; ++r) {
        const int m = rowBase + warpRow * 64 + i * 16 + q * 4 + r;
        const size_t idx = (size_t)m * N_ + n;
        const float base = first ? (resid[idx] + bv) : X[idx];
        X[idx] = base + acc[i][j][r];
      }
    }
  }
}

// ---------------------------------------------------------------------------
// Fused per-(b,route) pool: select tokens, LN+dot logits, masked softmax,
// weighted sum -> routes
// ---------------------------------------------------------------------------
__global__ __launch_bounds__(256) void route_pool_kernel(
    const float* __restrict__ X, const int* __restrict__ route_ids,
    const void* __restrict__ mask_raw, const int* __restrict__ flag,
    const float* __restrict__ gw, const float* __restrict__ gb,
    const float* __restrict__ ww, const float* __restrict__ wbias,
    float* __restrict__ routes, int* __restrict__ present) {
  const int b = blockIdx.x >> 5;
  const int r = blockIdx.x & 31;
  const int tid = threadIdx.x;
  __shared__ int cnt;
  __shared__ int ls[N_];
  __shared__ float lw[N_];
  if (tid == 0) cnt = 0;
  __syncthreads();
  const int fl = flag[0];
  for (int n = tid; n < N_; n += 256) {
    const int mk = fl ? (int)((const unsigned char*)mask_raw)[b * N_ + n]
                      : ((const int*)mask_raw)[b * N_ + n];
    if (route_ids[n] == r && mk != 0) {
      int p = atomicAdd(&cnt, 1);
      ls[p] = n;
    }
  }
  __syncthreads();
  const int c = cnt;
  const int wv = tid >> 6, lane = tid & 63;
  for (int t = wv; t < c; t += 4) {
    const float* p = X + ((size_t)b * N_ + ls[t]) * D_ + lane * 8;
    const float4 v0 = *(const float4*)p;
    const float4 v1 = *(const float4*)(p + 4);
    float s = v0.x + v0.y + v0.z + v0.w + v1.x + v1.y + v1.z + v1.w;
    float ss = v0.x * v0.x + v0.y * v0.y + v0.z * v0.z + v0.w * v0.w +
               v1.x * v1.x + v1.y * v1.y + v1.z * v1.z + v1.w * v1.w;
#pragma unroll
    for (int m = 32; m > 0; m >>= 1) {
      s += __shfl_xor(s, m);
      ss += __shfl_xor(ss, m);
    }
    const float mu = s * (1.0f / D_);
    const float rstd = rsqrtf(ss * (1.0f / D_) - mu * mu + 1e-5f);
    const float4 g0 = *(const float4*)(gw + lane * 8);
    const float4 g1 = *(const float4*)(gw + lane * 8 + 4);
    const float4 b0 = *(const float4*)(gb + lane * 8);
    const float4 b1v = *(const float4*)(gb + lane * 8 + 4);
    const float4 w0 = *(const float4*)(ww + lane * 8);
    const float4 w1v = *(const float4*)(ww + lane * 8 + 4);
    const float vv[8] = {v0.x, v0.y, v0.z, v0.w, v1.x, v1.y, v1.z, v1.w};
    const float gg[8] = {g0.x, g0.y, g0.z, g0.w, g1.x, g1.y, g1.z, g1.w};
    const float bb[8] = {b0.x, b0.y, b0.z, b0.w, b1v.x, b1v.y, b1v.z, b1v.w};
    const float wwv[8] = {w0.x, w0.y, w0.z, w0.w, w1v.x, w1v.y, w1v.z, w1v.w};
    float a = 0.f;
#pragma unroll
    for (int t2 = 0; t2 < 8; ++t2) a += ((vv[t2] - mu) * rstd * gg[t2] + bb[t2]) * wwv[t2];
#pragma unroll
    for (int m = 32; m > 0; m >>= 1) a += __shfl_xor(a, m);
    if (lane == 0) lw[t] = a + wbias[0];
  }
  __syncthreads();
  if (tid == 0 && c > 0) {
    float mx = -1e30f;
    for (int i = 0; i < c; ++i) mx = fmaxf(mx, lw[i]);
    float sm = 0.f;
    for (int i = 0; i < c; ++i) {
      const float e = __expf(lw[i] - mx);
      lw[i] = e;
      sm += e;
    }
    const float inv = 1.0f / sm;
    for (int i = 0; i < c; ++i) lw[i] *= inv;
  }
  __syncthreads();
  float a0 = 0.f, a1 = 0.f;
  for (int i = 0; i < c; ++i) {
    const float* xr = X + ((size_t)b * N_ + ls[i]) * D_;
    const float wgt = lw[i];
    a0 += wgt * xr[tid];
    a1 += wgt * xr[tid + 256];
  }
  float* outp = routes + ((size_t)b * R_ + r) * D_;
  outp[tid] = a0;
  outp[tid + 256] = a1;
  if (tid == 0) present[b * R_ + r] = (c > 0) ? 1 : 0;
}

// ---------------------------------------------------------------------------
// Final pool over routes (one block of 512 per batch)
// ---------------------------------------------------------------------------
__global__ __launch_bounds__(512) void final_pool_kernel(
    const float* __restrict__ routes, const int* __restrict__ present,
    const float* __restrict__ gw, const float* __restrict__ gb,
    const float* __restrict__ ww, const float* __restrict__ wbias,
    float* __restrict__ out) {
  const int b = blockIdx.x;
  const int wv = threadIdx.x >> 6, lane = threadIdx.x & 63;
  __shared__ float srw[R_];
  __shared__ float srl[R_];
  for (int r = wv; r < R_; r += 8) {
    const float* p = routes + ((size_t)b * R_ + r) * D_ + lane * 8;
    const float4 v0 = *(const float4*)p;
    const float4 v1 = *(const float4*)(p + 4);
    float s = v0.x + v0.y + v0.z + v0.w + v1.x + v1.y + v1.z + v1.w;
    float ss = v0.x * v0.x + v0.y * v0.y + v0.z * v0.z + v0.w * v0.w +
               v1.x * v1.x + v1.y * v1.y + v1.z * v1.z + v1.w * v1.w;
#pragma unroll
    for (int m = 32; m > 0; m >>= 1) {
      s += __shfl_xor(s, m);
      ss += __shfl_xor(ss, m);
    }
    const float mu = s * (1.0f / D_);
    const float rstd = rsqrtf(ss * (1.0f / D_) - mu * mu + 1e-5f);
    const float4 g0 = *(const float4*)(gw + lane * 8);
    const float4 g1 = *(const float4*)(gw + lane * 8 + 4);
    const float4 b0 = *(const float4*)(gb + lane * 8);
    const float4 b1v = *(const float4*)(gb + lane * 8 + 4);
    const float4 w0 = *(const float4*)(ww + lane * 8);
    const float4 w1v = *(const float4*)(ww + lane * 8 + 4);
    const float vv[8] = {v0.x, v0.y, v0.z, v0.w, v1.x, v1.y, v1.z, v1.w};
    const float gg[8] = {g0.x, g0.y, g0.z, g0.w, g1.x, g1.y, g1.z, g1.w};
    const float bb[8] = {b0.x, b0.y, b0.z, b0.w, b1v.x, b1v.y, b1v.z, b1v.w};
    const float wwv[8] = {w0.x, w0.y, w0.z, w0.w, w1v.x, w1v.y, w1v.z, w1v.w};
    float a = 0.f;
#pragma unroll
    for (int t = 0; t < 8; ++t) a += ((vv[t] - mu) * rstd * gg[t] + bb[t]) * wwv[t];
#pragma unroll
    for (int m = 32; m > 0; m >>= 1) a += __shfl_xor(a, m);
    if (lane == 0) srl[r] = a + wbias[0];
  }
  __syncthreads();
  if (threadIdx.x == 0) {
    float mx = -1e30f;
    for (int r = 0; r < R_; ++r)
      if (present[b * R_ + r]) mx = fmaxf(mx, srl[r]);
    float sm = 0.f;
    for (int r = 0; r < R_; ++r) {
      const float e = present[b * R_ + r] ? __expf(srl[r] - mx) : 0.f;
      srw[r] = e;
      sm += e;
    }
    const float inv = (sm > 0.f) ? 1.0f / sm : 0.f;
    for (int r = 0; r < R_; ++r) srw[r] *= inv;
  }
  __syncthreads();
  const int d = threadIdx.x;
  float a = 0.f;
  for (int r = 0; r < R_; ++r) a += srw[r] * routes[((size_t)b * R_ + r) * D_ + d];
  out[(size_t)b * D_ + d] = a;
}

// ---------------------------------------------------------------------------
extern "C" void kernel_launch(void* const* d_in, const int* in_sizes, int n_in,
                              void* d_out, int out_size, void* d_ws, size_t ws_size,
                              hipStream_t stream) {
  const float* tokens = (const float*)d_in[0];
  const void* mask_raw = d_in[1];
  const int* route_ids = (const int*)d_in[2];
  const float* ln1_g = (const float*)d_in[3];
  const float* ln1_b = (const float*)d_in[4];
  const float* w1 = (const float*)d_in[5];
  const float* b1 = (const float*)d_in[6];
  const float* w2 = (const float*)d_in[7];
  const float* b2 = (const float*)d_in[8];
  const float* wp_g = (const float*)d_in[9];
  const float* wp_b = (const float*)d_in[10];
  const float* wp_w = (const float*)d_in[11];
  const float* wp_bias = (const float*)d_in[12];
  const float* rp_g = (const float*)d_in[13];
  const float* rp_b = (const float*)d_in[14];
  const float* rp_w = (const float*)d_in[15];
  const float* rp_bias = (const float*)d_in[16];
  float* out = (float*)d_out;

  char* ws = (char*)d_ws;
  size_t off = 0;
  auto carve = [&](size_t bytes) -> void* {
    void* p = ws + off;
    off = (off + bytes + 255) & ~(size_t)255;
    return p;
  };

  __hip_bfloat16* w1t = (__hip_bfloat16*)carve((size_t)H_ * D_ * 2);  // [H, D]
  __hip_bfloat16* w2t = (__hip_bfloat16*)carve((size_t)D_ * H_ * 2);  // [D, H]
  __hip_bfloat16* aBf = (__hip_bfloat16*)carve((size_t)M_ * D_ * 2);  // LN1 out
  float* X = (float*)carve((size_t)M_ * D_ * 4);                      // FFN out
  int* flag = (int*)carve(256);
  int* present = (int*)carve((size_t)B_ * R_ * 4);
  float* routes = (float*)carve((size_t)B_ * R_ * D_ * 4);

  int G = 1;
  while (G < 16 && off + (size_t)M_ * (H_ / G) * 2 > ws_size) G <<= 1;
  const int Hg = H_ / G;
  __hip_bfloat16* hbuf = (__hip_bfloat16*)carve((size_t)M_ * Hg * 2);

  // one launch: mask detect + w1/w2 transpose-cast + LN
  prep_kernel<<<513 + M_ / 8, 512, 0, stream>>>(
      tokens, mask_raw, ln1_g, ln1_b, w1, w2, aBf, w1t, w2t, flag);

  const int NC1 = Hg / 128;
  for (int g = 0; g < G; ++g) {
    gemm_bias_gelu_kernel<<<(M_ / 128) * NC1, 256, 0, stream>>>(
        aBf, w1t + (size_t)g * Hg * D_, b1 + (size_t)g * Hg, hbuf, D_, Hg, NC1);
    gemm_acc_kernel<<<(M_ / 128) * 4, 256, 0, stream>>>(
        hbuf, w2t + (size_t)g * Hg, b2, tokens, X, Hg, H_, (g == 0) ? 1 : 0);
  }

  route_pool_kernel<<<B_ * R_, 256, 0, stream>>>(
      X, route_ids, mask_raw, flag, wp_g, wp_b, wp_w, wp_bias, routes, present);
  final_pool_kernel<<<B_, 512, 0, stream>>>(routes, present, rp_g, rp_b, rp_w, rp_bias, out);
}